// Round 1
// baseline (33281.921 us; speedup 1.0000x reference)
//
#include <hip/hip_runtime.h>
#include <hip/hip_bf16.h>
#include <math.h>

#define S_LEN 64
#define T_LEN 32
#define BATCH 512
#define IN_DIM 66
#define H_DIM 1024
#define O_DIM 1024
#define H3 3072

// ---------------------------------------------------------------------------
// Generic GEMM: C[M,N] = A[M,*lda] @ W[N,*ldw]^T  (+bias) (+C) (relu)
// flags: bit0 = add bias[n], bit1 = accumulate into existing C, bit2 = relu
// M, N must be multiples of 64 or exactly tile-covered (all our shapes are).
// ---------------------------------------------------------------------------
__global__ __launch_bounds__(256) void gemm_tn(
    const float* __restrict__ A, int lda,
    const float* __restrict__ W, int ldw,
    const float* __restrict__ bias,
    float* __restrict__ C, int ldc,
    int M, int N, int K, int flags)
{
    const int BM = 64, BN = 64, BK = 16;
    __shared__ float As[BK][BM + 1];
    __shared__ float Ws[BK][BN + 1];

    const int bm = blockIdx.y * BM;
    const int bn = blockIdx.x * BN;
    const int t  = threadIdx.x;          // 0..255
    const int tx = t & 15;
    const int ty = t >> 4;

    float acc[4][4] = {};

    for (int k0 = 0; k0 < K; k0 += BK) {
        #pragma unroll
        for (int j = 0; j < 4; j++) {
            int i = t + j * 256;         // 0..1023 covers 64x16 tile
            int r = i >> 4;
            int c = i & 15;
            int k = k0 + c;
            As[c][r] = (k < K) ? A[(size_t)(bm + r) * lda + k] : 0.f;
            Ws[c][r] = (k < K) ? W[(size_t)(bn + r) * ldw + k] : 0.f;
        }
        __syncthreads();
        #pragma unroll
        for (int kk = 0; kk < BK; kk++) {
            float a[4], b[4];
            #pragma unroll
            for (int i = 0; i < 4; i++) a[i] = As[kk][ty * 4 + i];
            #pragma unroll
            for (int i = 0; i < 4; i++) b[i] = Ws[kk][tx * 4 + i];
            #pragma unroll
            for (int i = 0; i < 4; i++)
                #pragma unroll
                for (int j = 0; j < 4; j++)
                    acc[i][j] += a[i] * b[j];
        }
        __syncthreads();
    }

    #pragma unroll
    for (int i = 0; i < 4; i++) {
        int m = bm + ty * 4 + i;
        #pragma unroll
        for (int j = 0; j < 4; j++) {
            int n = bn + tx * 4 + j;
            float v = acc[i][j];
            if (flags & 1) v += bias[n];
            if (flags & 2) v += C[(size_t)m * ldc + n];
            if (flags & 4) v = fmaxf(v, 0.f);
            C[(size_t)m * ldc + n] = v;
        }
    }
}

// ---------------------------------------------------------------------------
// Fused GRU cell elementwise: given gi=[B,3H] (x@Wih^T+bih), gh=[B,3H]
// (h@Whh^T+bhh), h=[B,H]; computes h' in-place into h; optionally also
// stores to enc_out slot.
// ---------------------------------------------------------------------------
__global__ void gru_fuse(const float* __restrict__ gi,
                         const float* __restrict__ gh,
                         float* __restrict__ h,
                         float* __restrict__ enc_slot)
{
    int idx = blockIdx.x * blockDim.x + threadIdx.x;
    if (idx >= BATCH * H_DIM) return;
    int b = idx >> 10;          // / H_DIM
    int i = idx & (H_DIM - 1);  // % H_DIM
    const float* gib = gi + (size_t)b * H3;
    const float* ghb = gh + (size_t)b * H3;
    float ir = gib[i], iz = gib[H_DIM + i], inn = gib[2 * H_DIM + i];
    float hr = ghb[i], hz = ghb[H_DIM + i], hn  = ghb[2 * H_DIM + i];
    float r = 1.f / (1.f + expf(-(ir + hr)));
    float z = 1.f / (1.f + expf(-(iz + hz)));
    float n = tanhf(inn + r * hn);
    float hv = h[idx];
    float o = (1.f - z) * n + z * hv;
    h[idx] = o;
    if (enc_slot) enc_slot[idx] = o;
}

// ---------------------------------------------------------------------------
// Row softmax over S_LEN=64 columns; one 64-lane wave per row, 4 rows/block.
// ---------------------------------------------------------------------------
__global__ void softmax64(float* __restrict__ x)
{
    int row  = blockIdx.x * 4 + (threadIdx.x >> 6);
    int lane = threadIdx.x & 63;
    float v = x[row * S_LEN + lane];
    float m = v;
    #pragma unroll
    for (int off = 32; off > 0; off >>= 1) m = fmaxf(m, __shfl_xor(m, off));
    float e = expf(v - m);
    float s = e;
    #pragma unroll
    for (int off = 32; off > 0; off >>= 1) s += __shfl_xor(s, off);
    x[row * S_LEN + lane] = e / s;
}

// ---------------------------------------------------------------------------
// ctx[b,h] = sum_l aw[b,l] * enc_out[l,b,h]
// ---------------------------------------------------------------------------
__global__ void ctx_kernel(const float* __restrict__ aw,
                           const float* __restrict__ enc_out,
                           float* __restrict__ ctx)
{
    int idx = blockIdx.x * blockDim.x + threadIdx.x;
    if (idx >= BATCH * H_DIM) return;
    int b  = idx >> 10;
    int hh = idx & (H_DIM - 1);
    const float* awb = aw + b * S_LEN;
    float s = 0.f;
    #pragma unroll 8
    for (int l = 0; l < S_LEN; l++)
        s += awb[l] * enc_out[((size_t)l * BATCH + b) * H_DIM + hh];
    ctx[idx] = s;
}

// ---------------------------------------------------------------------------
// In-place log_softmax over rows of O_DIM=1024; one 256-thread block per row.
// ---------------------------------------------------------------------------
__global__ void log_softmax1024(float* __restrict__ x)
{
    __shared__ float red[256];
    float* xr = x + (size_t)blockIdx.x * O_DIM;
    int t = threadIdx.x;
    float m = -1e30f;
    for (int i = t; i < O_DIM; i += 256) m = fmaxf(m, xr[i]);
    red[t] = m; __syncthreads();
    for (int s2 = 128; s2 > 0; s2 >>= 1) {
        if (t < s2) red[t] = fmaxf(red[t], red[t + s2]);
        __syncthreads();
    }
    m = red[0];
    __syncthreads();
    float s = 0.f;
    for (int i = t; i < O_DIM; i += 256) s += expf(xr[i] - m);
    red[t] = s; __syncthreads();
    for (int s2 = 128; s2 > 0; s2 >>= 1) {
        if (t < s2) red[t] += red[t + s2];
        __syncthreads();
    }
    float lse = m + logf(red[0]);
    __syncthreads();
    for (int i = t; i < O_DIM; i += 256) xr[i] = xr[i] - lse;
}

// ---------------------------------------------------------------------------
extern "C" void kernel_launch(void* const* d_in, const int* in_sizes, int n_in,
                              void* d_out, int out_size, void* d_ws, size_t ws_size,
                              hipStream_t stream)
{
    const float* input   = (const float*)d_in[0];   // [S,B,IN]
    const float* target  = (const float*)d_in[1];   // [T,B,H]
    const float* enc_Wih = (const float*)d_in[2];   // [3H,IN]
    const float* enc_Whh = (const float*)d_in[3];   // [3H,H]
    const float* enc_bih = (const float*)d_in[4];
    const float* enc_bhh = (const float*)d_in[5];
    const float* attn_W  = (const float*)d_in[6];   // [S,2H]
    const float* attn_b  = (const float*)d_in[7];
    const float* comb_W  = (const float*)d_in[8];   // [H,2H]
    const float* comb_b  = (const float*)d_in[9];
    const float* dec_Wih = (const float*)d_in[10];  // [3H,H]
    const float* dec_Whh = (const float*)d_in[11];  // [3H,H]
    const float* dec_bih = (const float*)d_in[12];
    const float* dec_bhh = (const float*)d_in[13];
    const float* out_W   = (const float*)d_in[14];  // [O,H]
    const float* out_b   = (const float*)d_in[15];
    float* out = (float*)d_out;                     // [B,O]

    // workspace layout (floats)
    float* enc_out = (float*)d_ws;                          // S*B*H   (128 MB)
    float* h    = enc_out + (size_t)S_LEN * BATCH * H_DIM;  // B*H
    float* gi   = h   + (size_t)BATCH * H_DIM;              // B*3H
    float* gh   = gi  + (size_t)BATCH * H3;                 // B*3H
    float* aw   = gh  + (size_t)BATCH * H3;                 // B*S
    float* ctx  = aw  + (size_t)BATCH * S_LEN;              // B*H
    float* comb = ctx + (size_t)BATCH * H_DIM;              // B*H

    hipMemsetAsync(h, 0, (size_t)BATCH * H_DIM * sizeof(float), stream);

    const dim3 blk(256);
    const dim3 grid_g3(H3 / 64, BATCH / 64);     // [B,3H] gemms
    const dim3 grid_gh(H_DIM / 64, BATCH / 64);  // [B,H] gemms
    const dim3 grid_gs(S_LEN / 64, BATCH / 64);  // [B,S] gemms
    const int  ew_grid = (BATCH * H_DIM) / 256;

    // ---------------- encoder ----------------
    for (int s = 0; s < S_LEN; s++) {
        const float* x = input + (size_t)s * BATCH * IN_DIM;
        gemm_tn<<<grid_g3, blk, 0, stream>>>(x, IN_DIM, enc_Wih, IN_DIM, enc_bih,
                                             gi, H3, BATCH, H3, IN_DIM, 1);
        gemm_tn<<<grid_g3, blk, 0, stream>>>(h, H_DIM, enc_Whh, H_DIM, enc_bhh,
                                             gh, H3, BATCH, H3, H_DIM, 1);
        gru_fuse<<<ew_grid, blk, 0, stream>>>(gi, gh, h,
                                              enc_out + (size_t)s * BATCH * H_DIM);
    }

    // ---------------- decoder (teacher forcing) ----------------
    for (int t = 0; t < T_LEN - 1; t++) {
        const float* x = target + (size_t)t * BATCH * H_DIM;
        // attention scores = [x,h] @ attn_W^T + attn_b
        gemm_tn<<<grid_gs, blk, 0, stream>>>(x, H_DIM, attn_W, 2 * H_DIM, attn_b,
                                             aw, S_LEN, BATCH, S_LEN, H_DIM, 1);
        gemm_tn<<<grid_gs, blk, 0, stream>>>(h, H_DIM, attn_W + H_DIM, 2 * H_DIM, nullptr,
                                             aw, S_LEN, BATCH, S_LEN, H_DIM, 2);
        softmax64<<<BATCH / 4, blk, 0, stream>>>(aw);
        ctx_kernel<<<ew_grid, blk, 0, stream>>>(aw, enc_out, ctx);
        // comb = relu([x,ctx] @ comb_W^T + comb_b)
        gemm_tn<<<grid_gh, blk, 0, stream>>>(x, H_DIM, comb_W, 2 * H_DIM, comb_b,
                                             comb, H_DIM, BATCH, H_DIM, H_DIM, 1);
        gemm_tn<<<grid_gh, blk, 0, stream>>>(ctx, H_DIM, comb_W + H_DIM, 2 * H_DIM, nullptr,
                                             comb, H_DIM, BATCH, H_DIM, H_DIM, 2 | 4);
        // GRU cell
        gemm_tn<<<grid_g3, blk, 0, stream>>>(comb, H_DIM, dec_Wih, H_DIM, dec_bih,
                                             gi, H3, BATCH, H3, H_DIM, 1);
        gemm_tn<<<grid_g3, blk, 0, stream>>>(h, H_DIM, dec_Whh, H_DIM, dec_bhh,
                                             gh, H3, BATCH, H3, H_DIM, 1);
        gru_fuse<<<ew_grid, blk, 0, stream>>>(gi, gh, h, nullptr);
    }

    // ---------------- output projection + log_softmax (last step only) ------
    gemm_tn<<<dim3(O_DIM / 64, BATCH / 64), blk, 0, stream>>>(
        h, H_DIM, out_W, H_DIM, out_b, out, O_DIM, BATCH, O_DIM, H_DIM, 1);
    log_softmax1024<<<BATCH, blk, 0, stream>>>(out);
}

// Round 2
// 6564.709 us; speedup vs baseline: 5.0698x; 5.0698x over previous
//
#include <hip/hip_runtime.h>
#include <hip/hip_bf16.h>
#include <math.h>

#define S_LEN 64
#define T_LEN 32
#define BATCH 512
#define IN_DIM 66
#define H_DIM 1024
#define O_DIM 1024
#define H3 3072

typedef __attribute__((ext_vector_type(8))) short short8;
typedef __attribute__((ext_vector_type(4))) float f32x4;
typedef __attribute__((ext_vector_type(4))) unsigned short us4;

__device__ __forceinline__ unsigned short f2b(float f) {
    union { float f; unsigned u; } x; x.f = f;
    unsigned r = x.u + 0x7FFF + ((x.u >> 16) & 1);
    return (unsigned short)(r >> 16);
}
__device__ __forceinline__ float b2f(unsigned short s) {
    union { unsigned u; float f; } x; x.u = ((unsigned)s) << 16;
    return x.f;
}
// async global->LDS, 16B per lane; lds base must be wave-uniform
__device__ __forceinline__ void gll16(const void* g, const void* l) {
    __builtin_amdgcn_global_load_lds(
        (const __attribute__((address_space(1))) unsigned int*)g,
        (__attribute__((address_space(3))) unsigned int*)l, 16, 0, 0);
}

// ---------------------------------------------------------------------------
// MFMA GEMM: C[M,N] = A[M,K] @ W[N,K]^T (+bias/+add/relu), tile 64(M) x TN(N)
// bf16 path: A,W bf16 (lda/ldw mult of 8), K mult of 32, global_load_lds.
// F32 path: A,W fp32, arbitrary lda/ldw, K guarded (zero-pad to mult of 32).
// Dual mode (A1v != null): rows >= Mhalf use A1/W1/bias1/Cf1.
// flags: 1 bias, 2 add fp32 mat, 4 add bf16 mat, 8 relu, 16 store f32, 32 store bf16
// ---------------------------------------------------------------------------
template<int TN, bool F32>
__global__ __launch_bounds__(256) void gemm_k(
    const void* __restrict__ A0v, const void* __restrict__ A1v, int lda,
    const void* __restrict__ W0v, const void* __restrict__ W1v, int ldw,
    const float* __restrict__ bias0, const float* __restrict__ bias1,
    const float* __restrict__ addf, const unsigned short* __restrict__ addb,
    int ldadd,
    float* __restrict__ Cf0, float* __restrict__ Cf1,
    unsigned short* __restrict__ Cb, int ldc,
    int K, int Mhalf, int flags)
{
    constexpr int JF = TN / 64;   // 16-col frags per wave
    constexpr int NW = TN / 4;    // cols per wave
    __shared__ __align__(16) unsigned short As[64 * 32];
    __shared__ __align__(16) unsigned short Bs[TN * 32];

    int bm = blockIdx.y * 64;
    const int bn = blockIdx.x * TN;
    const int t = threadIdx.x;
    const int lane = t & 63;
    const int wv = t >> 6;
    const int ln = lane & 15;
    const int quad = lane >> 4;

    const void* Av = A0v;
    const void* Wv = W0v;
    const float* bias = bias0;
    float* Cf = Cf0;
    if (A1v != nullptr && bm >= Mhalf) {
        Av = A1v; Wv = W1v; bias = bias1; Cf = Cf1; bm -= Mhalf;
    }

    f32x4 acc[4][JF];
    #pragma unroll
    for (int i = 0; i < 4; i++)
        #pragma unroll
        for (int j = 0; j < JF; j++) {
            f32x4 z = {0.f, 0.f, 0.f, 0.f};
            acc[i][j] = z;
        }

    const int Kp = (K + 31) & ~31;
    for (int k0 = 0; k0 < Kp; k0 += 32) {
        if constexpr (!F32) {
            const unsigned short* A = (const unsigned short*)Av;
            const unsigned short* W = (const unsigned short*)Wv;
            // A tile 64x32: 256 x 16B chunks, chunk t: row t>>2, colchunk t&3
            gll16(A + (size_t)(bm + (t >> 2)) * lda + k0 + (t & 3) * 8,
                  (const char*)As + wv * 1024);
            #pragma unroll
            for (int q = 0; q < TN / 64; q++) {
                int ch = q * 256 + t;
                gll16(W + (size_t)(bn + (ch >> 2)) * ldw + k0 + (ch & 3) * 8,
                      (const char*)Bs + q * 4096 + wv * 1024);
            }
        } else {
            const float* A = (const float*)Av;
            const float* W = (const float*)Wv;
            #pragma unroll
            for (int q = 0; q < 2; q++) {
                int e = (q * 256 + t) * 4;
                int r = e >> 5, c = e & 31;
                us4 u;
                #pragma unroll
                for (int i2 = 0; i2 < 4; i2++) {
                    int k = k0 + c + i2;
                    u[i2] = (k < K) ? f2b(A[(size_t)(bm + r) * lda + k]) : (unsigned short)0;
                }
                *(us4*)&As[r * 32 + c] = u;
            }
            #pragma unroll
            for (int q = 0; q < TN / 32; q++) {
                int e = (q * 256 + t) * 4;
                int r = e >> 5, c = e & 31;
                us4 u;
                #pragma unroll
                for (int i2 = 0; i2 < 4; i2++) {
                    int k = k0 + c + i2;
                    u[i2] = (k < K) ? f2b(W[(size_t)(bn + r) * ldw + k]) : (unsigned short)0;
                }
                *(us4*)&Bs[r * 32 + c] = u;
            }
        }
        __syncthreads();
        short8 af[4], bf[JF];
        #pragma unroll
        for (int i = 0; i < 4; i++)
            af[i] = *(const short8*)&As[(i * 16 + ln) * 32 + quad * 8];
        #pragma unroll
        for (int j = 0; j < JF; j++)
            bf[j] = *(const short8*)&Bs[(wv * NW + j * 16 + ln) * 32 + quad * 8];
        #pragma unroll
        for (int i = 0; i < 4; i++)
            #pragma unroll
            for (int j = 0; j < JF; j++)
                acc[i][j] = __builtin_amdgcn_mfma_f32_16x16x32_bf16(
                    af[i], bf[j], acc[i][j], 0, 0, 0);
        __syncthreads();
    }

    #pragma unroll
    for (int i = 0; i < 4; i++) {
        #pragma unroll
        for (int j = 0; j < JF; j++) {
            #pragma unroll
            for (int r = 0; r < 4; r++) {
                int m = bm + i * 16 + quad * 4 + r;
                int n = bn + wv * NW + j * 16 + ln;
                float v = acc[i][j][r];
                if (flags & 1) v += bias[n];
                if (flags & 2) v += addf[(size_t)m * ldadd + n];
                if (flags & 4) v += b2f(addb[(size_t)m * ldadd + n]);
                if (flags & 8) v = fmaxf(v, 0.f);
                if (flags & 16) Cf[(size_t)m * ldc + n] = v;
                if (flags & 32) Cb[(size_t)m * ldc + n] = f2b(v);
            }
        }
    }
}

// ---------------------------------------------------------------------------
// Fused attention: scores = h@attn_Wh^T + attn_x[t] (bias folded in attn_x),
// then row softmax over 64 cols -> aw fp32. One block per 64 batch rows.
// ---------------------------------------------------------------------------
__global__ __launch_bounds__(256) void attn_fused(
    const unsigned short* __restrict__ hb,    // [512,1024] bf16
    const unsigned short* __restrict__ wAh,   // [64,1024]  bf16
    const float* __restrict__ attn_x,         // [512,64] slice (incl. bias)
    float* __restrict__ aw)                   // [512,64]
{
    __shared__ __align__(16) unsigned short As[64 * 32];
    __shared__ __align__(16) unsigned short Bs[64 * 32];
    __shared__ float sc[64][68];
    const int bm = blockIdx.x * 64;
    const int t = threadIdx.x;
    const int lane = t & 63;
    const int wv = t >> 6;
    const int ln = lane & 15;
    const int quad = lane >> 4;

    f32x4 acc[4];
    #pragma unroll
    for (int i = 0; i < 4; i++) { f32x4 z = {0.f,0.f,0.f,0.f}; acc[i] = z; }

    for (int k0 = 0; k0 < H_DIM; k0 += 32) {
        gll16(hb + (size_t)(bm + (t >> 2)) * H_DIM + k0 + (t & 3) * 8,
              (const char*)As + wv * 1024);
        gll16(wAh + (size_t)(t >> 2) * H_DIM + k0 + (t & 3) * 8,
              (const char*)Bs + wv * 1024);
        __syncthreads();
        short8 af[4];
        #pragma unroll
        for (int i = 0; i < 4; i++)
            af[i] = *(const short8*)&As[(i * 16 + ln) * 32 + quad * 8];
        short8 bfr = *(const short8*)&Bs[(wv * 16 + ln) * 32 + quad * 8];
        #pragma unroll
        for (int i = 0; i < 4; i++)
            acc[i] = __builtin_amdgcn_mfma_f32_16x16x32_bf16(af[i], bfr, acc[i], 0, 0, 0);
        __syncthreads();
    }
    #pragma unroll
    for (int i = 0; i < 4; i++)
        #pragma unroll
        for (int r = 0; r < 4; r++) {
            int row = i * 16 + quad * 4 + r;
            int col = wv * 16 + ln;
            sc[row][col] = acc[i][r] + attn_x[(size_t)(bm + row) * S_LEN + col];
        }
    __syncthreads();
    // softmax: 4 threads per row, 16 cols each
    int r = t >> 2, p = t & 3;
    float mx = -1e30f;
    #pragma unroll
    for (int c = 0; c < 16; c++) mx = fmaxf(mx, sc[r][p * 16 + c]);
    mx = fmaxf(mx, __shfl_xor(mx, 1));
    mx = fmaxf(mx, __shfl_xor(mx, 2));
    float s = 0.f;
    #pragma unroll
    for (int c = 0; c < 16; c++) s += __expf(sc[r][p * 16 + c] - mx);
    s += __shfl_xor(s, 1);
    s += __shfl_xor(s, 2);
    float inv = 1.f / s;
    #pragma unroll
    for (int c = 0; c < 16; c++)
        aw[(size_t)(bm + r) * S_LEN + p * 16 + c] = __expf(sc[r][p * 16 + c] - mx) * inv;
}

// ---------------------------------------------------------------------------
// ctx[b,h] = sum_l aw[b,l] * enc_bf16[l,b,h]; one block per batch row.
// ---------------------------------------------------------------------------
__global__ __launch_bounds__(256) void ctx_k(
    const float* __restrict__ aw, const unsigned short* __restrict__ enc,
    unsigned short* __restrict__ ctx)
{
    __shared__ float awl[S_LEN];
    const int b = blockIdx.x, t = threadIdx.x;
    if (t < S_LEN) awl[t] = aw[b * S_LEN + t];
    __syncthreads();
    const int hq = t * 4;
    float s0 = 0.f, s1 = 0.f, s2 = 0.f, s3 = 0.f;
    #pragma unroll 4
    for (int l = 0; l < S_LEN; l++) {
        us4 u = *(const us4*)(enc + (((size_t)l * BATCH + b) << 10) + hq);
        float w = awl[l];
        s0 += w * b2f(u[0]); s1 += w * b2f(u[1]);
        s2 += w * b2f(u[2]); s3 += w * b2f(u[3]);
    }
    us4 o; o[0] = f2b(s0); o[1] = f2b(s1); o[2] = f2b(s2); o[3] = f2b(s3);
    *(us4*)(ctx + (((size_t)b) << 10) + hq) = o;
}

// ---------------------------------------------------------------------------
// GRU elementwise fuse: h' from gi, gh; writes h fp32 + bf16 (+enc slot)
// ---------------------------------------------------------------------------
__global__ void gru_fuse(const float* __restrict__ gi,
                         const float* __restrict__ gh,
                         float* __restrict__ h,
                         unsigned short* __restrict__ hb,
                         unsigned short* __restrict__ slot)
{
    int idx = blockIdx.x * blockDim.x + threadIdx.x;
    int b = idx >> 10, i = idx & (H_DIM - 1);
    const float* gib = gi + (size_t)b * H3;
    const float* ghb = gh + (size_t)b * H3;
    float ir = gib[i], iz = gib[H_DIM + i], inn = gib[2 * H_DIM + i];
    float hr = ghb[i], hz = ghb[H_DIM + i], hn = ghb[2 * H_DIM + i];
    float r = 1.f / (1.f + __expf(-(ir + hr)));
    float z = 1.f / (1.f + __expf(-(iz + hz)));
    float a = inn + r * hn;
    float e2 = __expf(-2.f * fabsf(a));
    float th = (1.f - e2) / (1.f + e2);
    th = a < 0.f ? -th : th;
    float o = (1.f - z) * th + z * h[idx];
    h[idx] = o;
    unsigned short ob = f2b(o);
    hb[idx] = ob;
    if (slot) slot[idx] = ob;
}

// strided fp32 -> compact bf16 weight convert
__global__ void cvt_w(const float* __restrict__ src, int ld,
                      unsigned short* __restrict__ dst, int rows, int cols)
{
    int idx = blockIdx.x * blockDim.x + threadIdx.x;
    if (idx >= rows * cols) return;
    int r = idx / cols, c = idx - r * cols;
    dst[idx] = f2b(src[(size_t)r * ld + c]);
}

__global__ void log_softmax1024(float* __restrict__ x)
{
    __shared__ float red[256];
    float* xr = x + (size_t)blockIdx.x * O_DIM;
    int t = threadIdx.x;
    float m = -1e30f;
    for (int i = t; i < O_DIM; i += 256) m = fmaxf(m, xr[i]);
    red[t] = m; __syncthreads();
    for (int s2 = 128; s2 > 0; s2 >>= 1) {
        if (t < s2) red[t] = fmaxf(red[t], red[t + s2]);
        __syncthreads();
    }
    m = red[0];
    __syncthreads();
    float s = 0.f;
    for (int i = t; i < O_DIM; i += 256) s += expf(xr[i] - m);
    red[t] = s; __syncthreads();
    for (int s2 = 128; s2 > 0; s2 >>= 1) {
        if (t < s2) red[t] += red[t + s2];
        __syncthreads();
    }
    float lse = m + logf(red[0]);
    __syncthreads();
    for (int i = t; i < O_DIM; i += 256) xr[i] = xr[i] - lse;
}

// ---------------------------------------------------------------------------
extern "C" void kernel_launch(void* const* d_in, const int* in_sizes, int n_in,
                              void* d_out, int out_size, void* d_ws, size_t ws_size,
                              hipStream_t stream)
{
    const float* input   = (const float*)d_in[0];   // [S,B,IN]
    const float* target  = (const float*)d_in[1];   // [T,B,H]
    const float* enc_Wih = (const float*)d_in[2];
    const float* enc_Whh = (const float*)d_in[3];
    const float* enc_bih = (const float*)d_in[4];
    const float* enc_bhh = (const float*)d_in[5];
    const float* attn_W  = (const float*)d_in[6];   // [S,2H]
    const float* attn_b  = (const float*)d_in[7];
    const float* comb_W  = (const float*)d_in[8];   // [H,2H]
    const float* comb_b  = (const float*)d_in[9];
    const float* dec_Wih = (const float*)d_in[10];
    const float* dec_Whh = (const float*)d_in[11];
    const float* dec_bih = (const float*)d_in[12];
    const float* dec_bhh = (const float*)d_in[13];
    const float* out_W   = (const float*)d_in[14];
    const float* out_b   = (const float*)d_in[15];
    float* out = (float*)d_out;                     // [B,O] fp32

    // ---- workspace layout (256B aligned chunks) ----
    char* p = (char*)d_ws;
    auto alloc = [&](size_t bytes) {
        char* r = p; p += (bytes + 255) & ~(size_t)255; return r;
    };
    unsigned short* wWhh   = (unsigned short*)alloc((size_t)H3 * H_DIM * 2);
    unsigned short* wDih   = (unsigned short*)alloc((size_t)H3 * H_DIM * 2);
    unsigned short* wDhh   = (unsigned short*)alloc((size_t)H3 * H_DIM * 2);
    unsigned short* wCc    = (unsigned short*)alloc((size_t)H_DIM * H_DIM * 2);
    unsigned short* wAh    = (unsigned short*)alloc((size_t)S_LEN * H_DIM * 2);
    unsigned short* wO     = (unsigned short*)alloc((size_t)O_DIM * H_DIM * 2);
    unsigned short* encb   = (unsigned short*)alloc((size_t)S_LEN * BATCH * H_DIM * 2);
    unsigned short* combx  = (unsigned short*)alloc((size_t)(T_LEN - 1) * BATCH * H_DIM * 2);
    float*          attnx  = (float*)alloc((size_t)(T_LEN - 1) * BATCH * S_LEN * 4);
    float*          h      = (float*)alloc((size_t)BATCH * H_DIM * 4);
    unsigned short* hb     = (unsigned short*)alloc((size_t)BATCH * H_DIM * 2);
    float*          gi     = (float*)alloc((size_t)BATCH * H3 * 4);
    float*          gh     = (float*)alloc((size_t)BATCH * H3 * 4);
    float*          aw     = (float*)alloc((size_t)BATCH * S_LEN * 4);
    unsigned short* ctx    = (unsigned short*)alloc((size_t)BATCH * H_DIM * 2);
    unsigned short* comb   = (unsigned short*)alloc((size_t)BATCH * H_DIM * 2);

    const dim3 blk(256);

    hipMemsetAsync(h,  0, (size_t)BATCH * H_DIM * 4, stream);
    hipMemsetAsync(hb, 0, (size_t)BATCH * H_DIM * 2, stream);

    // ---- one-time weight converts ----
    cvt_w<<<(H3 * H_DIM + 255) / 256, blk, 0, stream>>>(enc_Whh, H_DIM, wWhh, H3, H_DIM);
    cvt_w<<<(H3 * H_DIM + 255) / 256, blk, 0, stream>>>(dec_Wih, H_DIM, wDih, H3, H_DIM);
    cvt_w<<<(H3 * H_DIM + 255) / 256, blk, 0, stream>>>(dec_Whh, H_DIM, wDhh, H3, H_DIM);
    cvt_w<<<(H_DIM * H_DIM + 255) / 256, blk, 0, stream>>>(comb_W + H_DIM, 2 * H_DIM, wCc, H_DIM, H_DIM);
    cvt_w<<<(S_LEN * H_DIM + 255) / 256, blk, 0, stream>>>(attn_W + H_DIM, 2 * H_DIM, wAh, S_LEN, H_DIM);
    cvt_w<<<(O_DIM * H_DIM + 255) / 256, blk, 0, stream>>>(out_W, H_DIM, wO, O_DIM, H_DIM);

    const int MT = (T_LEN - 1) * BATCH;  // 15872 rows
    // attn_x = target @ attn_W[:, :H]^T + attn_b   (fp32 path)
    gemm_k<64, true><<<dim3(1, MT / 64), blk, 0, stream>>>(
        target, nullptr, H_DIM, attn_W, nullptr, 2 * H_DIM,
        attn_b, nullptr, nullptr, nullptr, 0,
        attnx, nullptr, nullptr, S_LEN, H_DIM, 0, 1 | 16);
    // comb_x = target @ comb_W[:, :H]^T + comb_b  -> bf16
    gemm_k<128, true><<<dim3(H_DIM / 128, MT / 64), blk, 0, stream>>>(
        target, nullptr, H_DIM, comb_W, nullptr, 2 * H_DIM,
        comb_b, nullptr, nullptr, nullptr, 0,
        nullptr, nullptr, combx, H_DIM, H_DIM, 0, 1 | 32);

    const dim3 g3(H3 / 128, BATCH / 64);     // 24 x 8
    const dim3 gH(H_DIM / 128, BATCH / 64);  // 8 x 8
    const int  ew = (BATCH * H_DIM) / 256;

    // ---------------- encoder ----------------
    for (int s = 0; s < S_LEN; s++) {
        const float* x = input + (size_t)s * BATCH * IN_DIM;
        gemm_k<128, true><<<g3, blk, 0, stream>>>(
            x, nullptr, IN_DIM, enc_Wih, nullptr, IN_DIM,
            enc_bih, nullptr, nullptr, nullptr, 0,
            gi, nullptr, nullptr, H3, IN_DIM, 0, 1 | 16);
        gemm_k<128, false><<<g3, blk, 0, stream>>>(
            hb, nullptr, H_DIM, wWhh, nullptr, H_DIM,
            enc_bhh, nullptr, nullptr, nullptr, 0,
            gh, nullptr, nullptr, H3, H_DIM, 0, 1 | 16);
        gru_fuse<<<ew, blk, 0, stream>>>(gi, gh, h, hb,
                                         encb + (size_t)s * BATCH * H_DIM);
    }

    // ---------------- decoder ----------------
    for (int t = 0; t < T_LEN - 1; t++) {
        attn_fused<<<BATCH / 64, blk, 0, stream>>>(
            hb, wAh, attnx + (size_t)t * BATCH * S_LEN, aw);
        ctx_k<<<BATCH, blk, 0, stream>>>(aw, encb, ctx);
        gemm_k<128, false><<<gH, blk, 0, stream>>>(
            ctx, nullptr, H_DIM, wCc, nullptr, H_DIM,
            nullptr, nullptr, nullptr, combx + (size_t)t * BATCH * H_DIM, H_DIM,
            nullptr, nullptr, comb, H_DIM, H_DIM, 0, 4 | 8 | 32);
        gemm_k<128, false><<<dim3(H3 / 128, 2 * BATCH / 64), blk, 0, stream>>>(
            comb, hb, H_DIM, wDih, wDhh, H_DIM,
            dec_bih, dec_bhh, nullptr, nullptr, 0,
            gi, gh, nullptr, H3, H_DIM, BATCH, 1 | 16);
        gru_fuse<<<ew, blk, 0, stream>>>(gi, gh, h, hb, nullptr);
    }

    // ---------------- output ----------------
    gemm_k<128, false><<<gH, blk, 0, stream>>>(
        hb, nullptr, H_DIM, wO, nullptr, H_DIM,
        out_b, nullptr, nullptr, nullptr, 0,
        out, nullptr, nullptr, O_DIM, H_DIM, 0, 1 | 16);
    log_softmax1024<<<BATCH, blk, 0, stream>>>(out);
}

// Round 3
// 4283.610 us; speedup vs baseline: 7.7696x; 1.5325x over previous
//
#include <hip/hip_runtime.h>
#include <hip/hip_bf16.h>
#include <math.h>

#define S_LEN 64
#define T_LEN 32
#define BATCH 512
#define IN_DIM 66
#define INP 96          // IN_DIM zero-padded to multiple of 32
#define H_DIM 1024
#define O_DIM 1024
#define H3 3072

typedef __attribute__((ext_vector_type(8))) short short8;
typedef __attribute__((ext_vector_type(4))) float f32x4;
typedef __attribute__((ext_vector_type(4))) unsigned short us4;

__device__ __forceinline__ unsigned short f2b(float f) {
    union { float f; unsigned u; } x; x.f = f;
    unsigned r = x.u + 0x7FFF + ((x.u >> 16) & 1);
    return (unsigned short)(r >> 16);
}
__device__ __forceinline__ float b2f(unsigned short s) {
    union { unsigned u; float f; } x; x.u = ((unsigned)s) << 16;
    return x.f;
}
// async global->LDS, 16B per lane; lds base must be wave-uniform
__device__ __forceinline__ void gll16(const void* g, const void* l) {
    __builtin_amdgcn_global_load_lds(
        (const __attribute__((address_space(1))) unsigned int*)g,
        (__attribute__((address_space(3))) unsigned int*)l, 16, 0, 0);
}

// ---------------------------------------------------------------------------
// Generic MFMA GEMM (round-2 proven): C[M,N] = A@W^T, tile 64 x TN.
// flags: 1 bias, 2 add fp32, 4 add bf16, 8 relu, 16 store f32, 32 store bf16
// ---------------------------------------------------------------------------
template<int TN, bool F32>
__global__ __launch_bounds__(256) void gemm_k(
    const void* __restrict__ A0v, int lda,
    const void* __restrict__ W0v, int ldw,
    const float* __restrict__ bias,
    const float* __restrict__ addf, const unsigned short* __restrict__ addb,
    int ldadd,
    float* __restrict__ Cf,
    unsigned short* __restrict__ Cb, int ldc,
    int K, int flags)
{
    constexpr int JF = TN / 64;
    constexpr int NW = TN / 4;
    __shared__ __align__(16) unsigned short As[64 * 32];
    __shared__ __align__(16) unsigned short Bs[TN * 32];

    const int bm = blockIdx.y * 64;
    const int bn = blockIdx.x * TN;
    const int t = threadIdx.x;
    const int lane = t & 63;
    const int wv = t >> 6;
    const int ln = lane & 15;
    const int quad = lane >> 4;

    f32x4 acc[4][JF];
    #pragma unroll
    for (int i = 0; i < 4; i++)
        #pragma unroll
        for (int j = 0; j < JF; j++) {
            f32x4 z = {0.f, 0.f, 0.f, 0.f};
            acc[i][j] = z;
        }

    const int Kp = (K + 31) & ~31;
    for (int k0 = 0; k0 < Kp; k0 += 32) {
        if constexpr (!F32) {
            const unsigned short* A = (const unsigned short*)A0v;
            const unsigned short* W = (const unsigned short*)W0v;
            gll16(A + (size_t)(bm + (t >> 2)) * lda + k0 + (t & 3) * 8,
                  (const char*)As + wv * 1024);
            #pragma unroll
            for (int q = 0; q < TN / 64; q++) {
                int ch = q * 256 + t;
                gll16(W + (size_t)(bn + (ch >> 2)) * ldw + k0 + (ch & 3) * 8,
                      (const char*)Bs + q * 4096 + wv * 1024);
            }
        } else {
            const float* A = (const float*)A0v;
            const float* W = (const float*)W0v;
            #pragma unroll
            for (int q = 0; q < 2; q++) {
                int e = (q * 256 + t) * 4;
                int r = e >> 5, c = e & 31;
                us4 u;
                #pragma unroll
                for (int i2 = 0; i2 < 4; i2++) {
                    int k = k0 + c + i2;
                    u[i2] = (k < K) ? f2b(A[(size_t)(bm + r) * lda + k]) : (unsigned short)0;
                }
                *(us4*)&As[r * 32 + c] = u;
            }
            #pragma unroll
            for (int q = 0; q < TN / 32; q++) {
                int e = (q * 256 + t) * 4;
                int r = e >> 5, c = e & 31;
                us4 u;
                #pragma unroll
                for (int i2 = 0; i2 < 4; i2++) {
                    int k = k0 + c + i2;
                    u[i2] = (k < K) ? f2b(W[(size_t)(bn + r) * ldw + k]) : (unsigned short)0;
                }
                *(us4*)&Bs[r * 32 + c] = u;
            }
        }
        __syncthreads();
        short8 af[4], bf[JF];
        #pragma unroll
        for (int i = 0; i < 4; i++)
            af[i] = *(const short8*)&As[(i * 16 + ln) * 32 + quad * 8];
        #pragma unroll
        for (int j = 0; j < JF; j++)
            bf[j] = *(const short8*)&Bs[(wv * NW + j * 16 + ln) * 32 + quad * 8];
        #pragma unroll
        for (int i = 0; i < 4; i++)
            #pragma unroll
            for (int j = 0; j < JF; j++)
                acc[i][j] = __builtin_amdgcn_mfma_f32_16x16x32_bf16(
                    af[i], bf[j], acc[i][j], 0, 0, 0);
        __syncthreads();
    }

    #pragma unroll
    for (int i = 0; i < 4; i++) {
        #pragma unroll
        for (int j = 0; j < JF; j++) {
            #pragma unroll
            for (int r = 0; r < 4; r++) {
                int m = bm + i * 16 + quad * 4 + r;
                int n = bn + wv * NW + j * 16 + ln;
                float v = acc[i][j][r];
                if (flags & 1) v += bias[n];
                if (flags & 2) v += addf[(size_t)m * ldadd + n];
                if (flags & 4) v += b2f(addb[(size_t)m * ldadd + n]);
                if (flags & 8) v = fmaxf(v, 0.f);
                if (flags & 16) Cf[(size_t)m * ldc + n] = v;
                if (flags & 32) Cb[(size_t)m * ldc + n] = f2b(v);
            }
        }
    }
}

// ---------------------------------------------------------------------------
// One GEMM phase of the fused GRU step: accumulates A@W_r, A@W_z, A@W_n
// into accR/accZ/accN for a 32(batch) x 64(gate col) tile. Inlined twice.
// ---------------------------------------------------------------------------
__device__ __forceinline__ void gru_phase(
    const unsigned short* __restrict__ A, int lda,
    const unsigned short* __restrict__ W, int ldw, int K,
    unsigned short* As, unsigned short* Ws,
    int bm, int bn, int t, int wv, int ln, int quad,
    f32x4 (&accR)[2], f32x4 (&accZ)[2], f32x4 (&accN)[2])
{
    for (int k0 = 0; k0 < K; k0 += 32) {
        if (wv < 2)
            gll16(A + (size_t)(bm + (t >> 2)) * lda + k0 + (t & 3) * 8,
                  (const char*)As + wv * 1024);
        #pragma unroll
        for (int g = 0; g < 3; g++)
            gll16(W + (size_t)(g * H_DIM + bn + (t >> 2)) * ldw + k0 + (t & 3) * 8,
                  (const char*)Ws + g * 4096 + wv * 1024);
        __syncthreads();
        short8 a[2], bw[3];
        #pragma unroll
        for (int i = 0; i < 2; i++)
            a[i] = *(const short8*)&As[(i * 16 + ln) * 32 + quad * 8];
        #pragma unroll
        for (int g = 0; g < 3; g++)
            bw[g] = *(const short8*)&Ws[g * 2048 + (wv * 16 + ln) * 32 + quad * 8];
        #pragma unroll
        for (int i = 0; i < 2; i++) {
            accR[i] = __builtin_amdgcn_mfma_f32_16x16x32_bf16(a[i], bw[0], accR[i], 0, 0, 0);
            accZ[i] = __builtin_amdgcn_mfma_f32_16x16x32_bf16(a[i], bw[1], accZ[i], 0, 0, 0);
            accN[i] = __builtin_amdgcn_mfma_f32_16x16x32_bf16(a[i], bw[2], accN[i], 0, 0, 0);
        }
        __syncthreads();
    }
}

// ---------------------------------------------------------------------------
// Fused GRU step: h' = GRU(x, h). Computes x@Wih^T (3 gates) + h@Whh^T
// (3 gates) + full elementwise, writes h fp32 (in-place safe: each element
// touched by exactly one lane) + bf16 shadow (ping-pong) + optional enc slot.
// Tile: 32 batch rows x 64 gate cols; grid (16, 16) = 256 blocks.
// ---------------------------------------------------------------------------
__global__ __launch_bounds__(256) void gru_gemm(
    const unsigned short* __restrict__ A0, int lda0,
    const unsigned short* __restrict__ W0, int ldw0, int K0,
    const unsigned short* __restrict__ A1,   // hb_in [512,1024]
    const unsigned short* __restrict__ W1,   // Whh   [3072,1024]
    const float* __restrict__ bih, const float* __restrict__ bhh,
    const float* __restrict__ hf_in, float* __restrict__ hf_out,
    unsigned short* __restrict__ hb_out, unsigned short* __restrict__ slot)
{
    __shared__ __align__(16) unsigned short As[32 * 32];
    __shared__ __align__(16) unsigned short Ws[3 * 64 * 32];
    const int bm = blockIdx.y * 32;
    const int bn = blockIdx.x * 64;
    const int t = threadIdx.x;
    const int lane = t & 63;
    const int wv = t >> 6;
    const int ln = lane & 15;
    const int quad = lane >> 4;

    f32x4 accR[2], accZ[2], accN0[2], accN1[2];
    #pragma unroll
    for (int i = 0; i < 2; i++) {
        f32x4 z = {0.f, 0.f, 0.f, 0.f};
        accR[i] = z; accZ[i] = z; accN0[i] = z; accN1[i] = z;
    }

    gru_phase(A0, lda0, W0, ldw0, K0, As, Ws, bm, bn, t, wv, ln, quad,
              accR, accZ, accN0);
    gru_phase(A1, H_DIM, W1, H_DIM, H_DIM, As, Ws, bm, bn, t, wv, ln, quad,
              accR, accZ, accN1);

    const int n = bn + wv * 16 + ln;
    const float br = bih[n] + bhh[n];
    const float bz = bih[H_DIM + n] + bhh[H_DIM + n];
    const float bi_n = bih[2 * H_DIM + n];
    const float bh_n = bhh[2 * H_DIM + n];
    #pragma unroll
    for (int i = 0; i < 2; i++) {
        #pragma unroll
        for (int r = 0; r < 4; r++) {
            const int m = bm + i * 16 + quad * 4 + r;
            const size_t idx = (size_t)m * H_DIM + n;
            float rg = 1.f / (1.f + __expf(-(accR[i][r] + br)));
            float zg = 1.f / (1.f + __expf(-(accZ[i][r] + bz)));
            float av = accN0[i][r] + bi_n + rg * (accN1[i][r] + bh_n);
            float e2 = __expf(-2.f * fabsf(av));
            float th = (1.f - e2) / (1.f + e2);
            th = av < 0.f ? -th : th;
            float o = (1.f - zg) * th + zg * hf_in[idx];
            hf_out[idx] = o;
            unsigned short ob = f2b(o);
            hb_out[idx] = ob;
            if (slot) slot[idx] = ob;
        }
    }
}

// ---------------------------------------------------------------------------
// Fused attention: one block per batch row. scores = h.wAhT + attnx (bf16),
// softmax over 64, then ctx[b,:] = sum_l aw[l] * enc[l,b,:]. 512 blocks.
// ---------------------------------------------------------------------------
__global__ __launch_bounds__(256) void attn_ctx(
    const unsigned short* __restrict__ hb,     // [512,1024] bf16
    const unsigned short* __restrict__ wAhT,   // [1024][64] bf16 (k-major)
    const unsigned short* __restrict__ attnx_t,// [512,64] bf16 (incl bias)
    const unsigned short* __restrict__ encb,   // [64,512,1024] bf16
    unsigned short* __restrict__ ctx)          // [512,1024] bf16
{
    __shared__ float hf[H_DIM];
    __shared__ float part[4][S_LEN];
    __shared__ float awl[S_LEN];
    const int b = blockIdx.x, t = threadIdx.x;
    {
        us4 u = *(const us4*)(hb + ((size_t)b << 10) + t * 4);
        #pragma unroll
        for (int j = 0; j < 4; j++) hf[t * 4 + j] = b2f(u[j]);
    }
    __syncthreads();
    // scores: thread t handles col t&63, K-slice (t>>6)*256
    {
        const int c = t & 63, ks = (t >> 6) * 256;
        float s = 0.f;
        #pragma unroll 8
        for (int k = 0; k < 256; k++)
            s += hf[ks + k] * b2f(wAhT[(size_t)(ks + k) * S_LEN + c]);
        part[t >> 6][c] = s;
    }
    __syncthreads();
    if (t < 64) {   // wave 0 does the softmax
        float v = part[0][t] + part[1][t] + part[2][t] + part[3][t]
                + b2f(attnx_t[b * S_LEN + t]);
        float m = v;
        #pragma unroll
        for (int off = 32; off; off >>= 1) m = fmaxf(m, __shfl_xor(m, off));
        float e = __expf(v - m);
        float ss = e;
        #pragma unroll
        for (int off = 32; off; off >>= 1) ss += __shfl_xor(ss, off);
        awl[t] = e / ss;
    }
    __syncthreads();
    const int hq = t * 4;
    float s0 = 0.f, s1 = 0.f, s2 = 0.f, s3 = 0.f;
    #pragma unroll 4
    for (int l = 0; l < S_LEN; l++) {
        us4 u = *(const us4*)(encb + (((size_t)l * BATCH + b) << 10) + hq);
        float w = awl[l];
        s0 += w * b2f(u[0]); s1 += w * b2f(u[1]);
        s2 += w * b2f(u[2]); s3 += w * b2f(u[3]);
    }
    us4 o; o[0] = f2b(s0); o[1] = f2b(s1); o[2] = f2b(s2); o[3] = f2b(s3);
    *(us4*)(ctx + ((size_t)b << 10) + hq) = o;
}

// strided fp32 -> compact bf16 weight convert
__global__ void cvt_w(const float* __restrict__ src, int ld,
                      unsigned short* __restrict__ dst, int rows, int cols)
{
    int idx = blockIdx.x * blockDim.x + threadIdx.x;
    if (idx >= rows * cols) return;
    int r = idx / cols, c = idx - r * cols;
    dst[idx] = f2b(src[(size_t)r * ld + c]);
}

// fp32 [rows, scols] -> bf16 [rows, dcols] zero-padded
__global__ void cvt_pad(const float* __restrict__ src, int scols,
                        unsigned short* __restrict__ dst, int dcols, int total)
{
    int idx = blockIdx.x * blockDim.x + threadIdx.x;
    if (idx >= total) return;
    int r = idx / dcols, c = idx - r * dcols;
    dst[idx] = (c < scols) ? f2b(src[(size_t)r * scols + c]) : (unsigned short)0;
}

// attn_W[:, H:2H] fp32 [64, ld 2048] -> wAhT bf16 [k][c]
__global__ void cvt_attT(const float* __restrict__ attn_W,
                         unsigned short* __restrict__ dst)
{
    int idx = blockIdx.x * blockDim.x + threadIdx.x;
    if (idx >= S_LEN * H_DIM) return;
    int k = idx >> 6, c = idx & 63;
    dst[idx] = f2b(attn_W[(size_t)c * 2 * H_DIM + H_DIM + k]);
}

__global__ void log_softmax1024(float* __restrict__ x)
{
    __shared__ float red[256];
    float* xr = x + (size_t)blockIdx.x * O_DIM;
    int t = threadIdx.x;
    float m = -1e30f;
    for (int i = t; i < O_DIM; i += 256) m = fmaxf(m, xr[i]);
    red[t] = m; __syncthreads();
    for (int s2 = 128; s2 > 0; s2 >>= 1) {
        if (t < s2) red[t] = fmaxf(red[t], red[t + s2]);
        __syncthreads();
    }
    m = red[0];
    __syncthreads();
    float s = 0.f;
    for (int i = t; i < O_DIM; i += 256) s += expf(xr[i] - m);
    red[t] = s; __syncthreads();
    for (int s2 = 128; s2 > 0; s2 >>= 1) {
        if (t < s2) red[t] += red[t + s2];
        __syncthreads();
    }
    float lse = m + logf(red[0]);
    __syncthreads();
    for (int i = t; i < O_DIM; i += 256) xr[i] = xr[i] - lse;
}

// ---------------------------------------------------------------------------
extern "C" void kernel_launch(void* const* d_in, const int* in_sizes, int n_in,
                              void* d_out, int out_size, void* d_ws, size_t ws_size,
                              hipStream_t stream)
{
    const float* input   = (const float*)d_in[0];   // [S,B,IN]
    const float* target  = (const float*)d_in[1];   // [T,B,H]
    const float* enc_Wih = (const float*)d_in[2];
    const float* enc_Whh = (const float*)d_in[3];
    const float* enc_bih = (const float*)d_in[4];
    const float* enc_bhh = (const float*)d_in[5];
    const float* attn_W  = (const float*)d_in[6];   // [S,2H]
    const float* attn_b  = (const float*)d_in[7];
    const float* comb_W  = (const float*)d_in[8];   // [H,2H]
    const float* comb_b  = (const float*)d_in[9];
    const float* dec_Wih = (const float*)d_in[10];
    const float* dec_Whh = (const float*)d_in[11];
    const float* dec_bih = (const float*)d_in[12];
    const float* dec_bhh = (const float*)d_in[13];
    const float* out_W   = (const float*)d_in[14];
    const float* out_b   = (const float*)d_in[15];
    float* out = (float*)d_out;                     // [B,O] fp32

    // ---- workspace layout ----
    char* p = (char*)d_ws;
    auto alloc = [&](size_t bytes) {
        char* r = p; p += (bytes + 255) & ~(size_t)255; return r;
    };
    unsigned short* wWhh  = (unsigned short*)alloc((size_t)H3 * H_DIM * 2);
    unsigned short* wDih  = (unsigned short*)alloc((size_t)H3 * H_DIM * 2);
    unsigned short* wDhh  = (unsigned short*)alloc((size_t)H3 * H_DIM * 2);
    unsigned short* wCc   = (unsigned short*)alloc((size_t)H_DIM * H_DIM * 2);
    unsigned short* wO    = (unsigned short*)alloc((size_t)O_DIM * H_DIM * 2);
    unsigned short* wAhT  = (unsigned short*)alloc((size_t)H_DIM * S_LEN * 2);
    unsigned short* wIhp  = (unsigned short*)alloc((size_t)H3 * INP * 2);
    unsigned short* xbp   = (unsigned short*)alloc((size_t)S_LEN * BATCH * INP * 2);
    unsigned short* encb  = (unsigned short*)alloc((size_t)S_LEN * BATCH * H_DIM * 2);
    unsigned short* combx = (unsigned short*)alloc((size_t)(T_LEN - 1) * BATCH * H_DIM * 2);
    unsigned short* attnx = (unsigned short*)alloc((size_t)(T_LEN - 1) * BATCH * S_LEN * 2);
    float*          h     = (float*)alloc((size_t)BATCH * H_DIM * 4);
    unsigned short* hbA   = (unsigned short*)alloc((size_t)BATCH * H_DIM * 2);
    unsigned short* hbB   = (unsigned short*)alloc((size_t)BATCH * H_DIM * 2);
    unsigned short* ctx   = (unsigned short*)alloc((size_t)BATCH * H_DIM * 2);
    unsigned short* comb  = (unsigned short*)alloc((size_t)BATCH * H_DIM * 2);

    const dim3 blk(256);

    hipMemsetAsync(h,   0, (size_t)BATCH * H_DIM * 4, stream);
    hipMemsetAsync(hbA, 0, (size_t)BATCH * H_DIM * 2, stream);

    // ---- one-time converts ----
    cvt_w<<<(H3 * H_DIM + 255) / 256, blk, 0, stream>>>(enc_Whh, H_DIM, wWhh, H3, H_DIM);
    cvt_w<<<(H3 * H_DIM + 255) / 256, blk, 0, stream>>>(dec_Wih, H_DIM, wDih, H3, H_DIM);
    cvt_w<<<(H3 * H_DIM + 255) / 256, blk, 0, stream>>>(dec_Whh, H_DIM, wDhh, H3, H_DIM);
    cvt_w<<<(H_DIM * H_DIM + 255) / 256, blk, 0, stream>>>(comb_W + H_DIM, 2 * H_DIM, wCc, H_DIM, H_DIM);
    cvt_w<<<(O_DIM * H_DIM + 255) / 256, blk, 0, stream>>>(out_W, H_DIM, wO, O_DIM, H_DIM);
    cvt_attT<<<(S_LEN * H_DIM + 255) / 256, blk, 0, stream>>>(attn_W, wAhT);
    cvt_pad<<<((S_LEN * BATCH * INP) + 255) / 256, blk, 0, stream>>>(
        input, IN_DIM, xbp, INP, S_LEN * BATCH * INP);
    cvt_pad<<<((H3 * INP) + 255) / 256, blk, 0, stream>>>(
        enc_Wih, IN_DIM, wIhp, INP, H3 * INP);

    const int MT = (T_LEN - 1) * BATCH;  // 15872
    // attnx = target @ attn_W[:, :H]^T + attn_b  -> bf16
    gemm_k<64, true><<<dim3(1, MT / 64), blk, 0, stream>>>(
        target, H_DIM, attn_W, 2 * H_DIM, attn_b,
        nullptr, nullptr, 0, nullptr, attnx, S_LEN, H_DIM, 1 | 32);
    // combx = target @ comb_W[:, :H]^T + comb_b  -> bf16
    gemm_k<128, true><<<dim3(H_DIM / 128, MT / 64), blk, 0, stream>>>(
        target, H_DIM, comb_W, 2 * H_DIM, comb_b,
        nullptr, nullptr, 0, nullptr, combx, H_DIM, H_DIM, 1 | 32);

    const dim3 grid_gru(H_DIM / 64, BATCH / 32);   // 16 x 16 = 256 blocks
    unsigned short* hcur = hbA;
    unsigned short* hnxt = hbB;

    // ---------------- encoder: one kernel per step ----------------
    for (int s = 0; s < S_LEN; s++) {
        gru_gemm<<<grid_gru, blk, 0, stream>>>(
            xbp + (size_t)s * BATCH * INP, INP, wIhp, INP, INP,
            hcur, wWhh, enc_bih, enc_bhh, h, h, hnxt,
            encb + (size_t)s * BATCH * H_DIM);
        unsigned short* tmp = hcur; hcur = hnxt; hnxt = tmp;
    }

    // ---------------- decoder: three kernels per step ----------------
    for (int t = 0; t < T_LEN - 1; t++) {
        attn_ctx<<<BATCH, blk, 0, stream>>>(
            hcur, wAhT, attnx + (size_t)t * BATCH * S_LEN, encb, ctx);
        gemm_k<64, false><<<dim3(H_DIM / 64, BATCH / 64), blk, 0, stream>>>(
            ctx, H_DIM, wCc, H_DIM, nullptr,
            nullptr, combx + (size_t)t * BATCH * H_DIM, H_DIM,
            nullptr, comb, H_DIM, H_DIM, 4 | 8 | 32);
        gru_gemm<<<grid_gru, blk, 0, stream>>>(
            comb, H_DIM, wDih, H_DIM, H_DIM,
            hcur, wDhh, dec_bih, dec_bhh, h, h, hnxt, nullptr);
        unsigned short* tmp = hcur; hcur = hnxt; hnxt = tmp;
    }

    // ---------------- output ----------------
    gemm_k<64, false><<<dim3(O_DIM / 64, BATCH / 64), blk, 0, stream>>>(
        hcur, H_DIM, wO, H_DIM, out_b,
        nullptr, nullptr, 0, out, nullptr, O_DIM, H_DIM, 1 | 16);
    log_softmax1024<<<BATCH, blk, 0, stream>>>(out);
}

// Round 4
// 3642.385 us; speedup vs baseline: 9.1374x; 1.1760x over previous
//
#include <hip/hip_runtime.h>
#include <hip/hip_bf16.h>
#include <math.h>

#define S_LEN 64
#define T_LEN 32
#define BATCH 512
#define IN_DIM 66
#define INP 128         // IN_DIM zero-padded to multiple of 64
#define H_DIM 1024
#define O_DIM 1024
#define H3 3072

typedef __attribute__((ext_vector_type(8))) short short8;
typedef __attribute__((ext_vector_type(4))) float f32x4;
typedef __attribute__((ext_vector_type(4))) unsigned short us4;

__device__ __forceinline__ unsigned short f2b(float f) {
    union { float f; unsigned u; } x; x.f = f;
    unsigned r = x.u + 0x7FFF + ((x.u >> 16) & 1);
    return (unsigned short)(r >> 16);
}
__device__ __forceinline__ float b2f(unsigned short s) {
    union { unsigned u; float f; } x; x.u = ((unsigned)s) << 16;
    return x.f;
}
// async global->LDS, 16B per lane; lds base must be wave-uniform
__device__ __forceinline__ void gll16(const void* g, const void* l) {
    __builtin_amdgcn_global_load_lds(
        (const __attribute__((address_space(1))) unsigned int*)g,
        (__attribute__((address_space(3))) unsigned int*)l, 16, 0, 0);
}

// ---------------------------------------------------------------------------
// MFMA GEMM, bf16: C[M,N] = A@W^T, tile 64 x TN. lda/ldw mult of 8, K mult 32.
// flags: 1 bias, 2 add fp32, 4 add bf16, 8 relu, 16 store f32, 32 store bf16
// ---------------------------------------------------------------------------
template<int TN>
__global__ __launch_bounds__(256) void gemm_k(
    const unsigned short* __restrict__ A, int lda,
    const unsigned short* __restrict__ W, int ldw,
    const float* __restrict__ bias,
    const float* __restrict__ addf, const unsigned short* __restrict__ addb,
    int ldadd,
    float* __restrict__ Cf,
    unsigned short* __restrict__ Cb, int ldc,
    int K, int flags)
{
    constexpr int JF = TN / 64;
    constexpr int NW = TN / 4;
    __shared__ __align__(16) unsigned short As[64 * 32];
    __shared__ __align__(16) unsigned short Bs[TN * 32];

    const int bm = blockIdx.y * 64;
    const int bn = blockIdx.x * TN;
    const int t = threadIdx.x;
    const int lane = t & 63;
    const int wv = t >> 6;
    const int ln = lane & 15;
    const int quad = lane >> 4;

    f32x4 acc[4][JF];
    #pragma unroll
    for (int i = 0; i < 4; i++)
        #pragma unroll
        for (int j = 0; j < JF; j++) {
            f32x4 z = {0.f, 0.f, 0.f, 0.f};
            acc[i][j] = z;
        }

    for (int k0 = 0; k0 < K; k0 += 32) {
        gll16(A + (size_t)(bm + (t >> 2)) * lda + k0 + (t & 3) * 8,
              (const char*)As + wv * 1024);
        #pragma unroll
        for (int q = 0; q < TN / 64; q++) {
            int ch = q * 256 + t;
            gll16(W + (size_t)(bn + (ch >> 2)) * ldw + k0 + (ch & 3) * 8,
                  (const char*)Bs + q * 4096 + wv * 1024);
        }
        __syncthreads();
        short8 af[4], bf[JF];
        #pragma unroll
        for (int i = 0; i < 4; i++)
            af[i] = *(const short8*)&As[(i * 16 + ln) * 32 + quad * 8];
        #pragma unroll
        for (int j = 0; j < JF; j++)
            bf[j] = *(const short8*)&Bs[(wv * NW + j * 16 + ln) * 32 + quad * 8];
        #pragma unroll
        for (int i = 0; i < 4; i++)
            #pragma unroll
            for (int j = 0; j < JF; j++)
                acc[i][j] = __builtin_amdgcn_mfma_f32_16x16x32_bf16(
                    af[i], bf[j], acc[i][j], 0, 0, 0);
        __syncthreads();
    }

    #pragma unroll
    for (int i = 0; i < 4; i++) {
        #pragma unroll
        for (int j = 0; j < JF; j++) {
            #pragma unroll
            for (int r = 0; r < 4; r++) {
                int m = bm + i * 16 + quad * 4 + r;
                int n = bn + wv * NW + j * 16 + ln;
                float v = acc[i][j][r];
                if (flags & 1) v += bias[n];
                if (flags & 2) v += addf[(size_t)m * ldadd + n];
                if (flags & 4) v += b2f(addb[(size_t)m * ldadd + n]);
                if (flags & 8) v = fmaxf(v, 0.f);
                if (flags & 16) Cf[(size_t)m * ldc + n] = v;
                if (flags & 32) Cb[(size_t)m * ldc + n] = f2b(v);
            }
        }
    }
}

// ---------------------------------------------------------------------------
// GRU GEMM phase, BK=64 staged as two BK=32 subtiles (keeps m97-style 64B
// row stride -> no extra LDS bank conflicts; padding would break gll16).
// As2: [2][32][32] shorts (4 KB), Ws2: [3][2][64][32] shorts (24 KB).
// K must be a multiple of 64.
// ---------------------------------------------------------------------------
__device__ __forceinline__ void gru_phase64(
    const unsigned short* __restrict__ A, int lda,
    const unsigned short* __restrict__ W, int ldw, int K,
    unsigned short* As2, unsigned short* Ws2,
    int bm, int bn, int t, int wv, int ln, int quad,
    f32x4 (&accR)[2], f32x4 (&accZ)[2], f32x4 (&accN)[2])
{
    for (int k0 = 0; k0 < K; k0 += 64) {
        // A: chunk t -> sub t>>7, row (t>>2)&31, kchunk t&3; dest byte = t*16
        {
            int s = t >> 7, r = (t >> 2) & 31, c = t & 3;
            gll16(A + (size_t)(bm + r) * lda + k0 + s * 32 + c * 8,
                  (const char*)As2 + wv * 1024);
        }
        // W: per gate 512 chunks: ch -> sub ch>>8, row (ch>>2)&63, kchunk ch&3
        #pragma unroll
        for (int g = 0; g < 3; g++) {
            #pragma unroll
            for (int hf2 = 0; hf2 < 2; hf2++) {
                int ch = hf2 * 256 + t;
                int s = ch >> 8, r = (ch >> 2) & 63, c = ch & 3;
                gll16(W + (size_t)(g * H_DIM + bn + r) * ldw + k0 + s * 32 + c * 8,
                      (const char*)Ws2 + g * 8192 + hf2 * 4096 + wv * 1024);
            }
        }
        __syncthreads();
        #pragma unroll
        for (int sub = 0; sub < 2; sub++) {
            short8 a[2], bw[3];
            #pragma unroll
            for (int i = 0; i < 2; i++)
                a[i] = *(const short8*)&As2[sub * 1024 + (i * 16 + ln) * 32 + quad * 8];
            #pragma unroll
            for (int g = 0; g < 3; g++)
                bw[g] = *(const short8*)&Ws2[g * 4096 + sub * 2048 + (wv * 16 + ln) * 32 + quad * 8];
            #pragma unroll
            for (int i = 0; i < 2; i++) {
                accR[i] = __builtin_amdgcn_mfma_f32_16x16x32_bf16(a[i], bw[0], accR[i], 0, 0, 0);
                accZ[i] = __builtin_amdgcn_mfma_f32_16x16x32_bf16(a[i], bw[1], accZ[i], 0, 0, 0);
                accN[i] = __builtin_amdgcn_mfma_f32_16x16x32_bf16(a[i], bw[2], accN[i], 0, 0, 0);
            }
        }
        __syncthreads();
    }
}

// ---------------------------------------------------------------------------
// Fused GRU step: h' = GRU(x, h); 32 batch rows x 64 gate cols per block,
// grid (16,16) = 256 blocks. Writes h fp32 in-place + bf16 shadow + enc slot.
// ---------------------------------------------------------------------------
__global__ __launch_bounds__(256) void gru_gemm(
    const unsigned short* __restrict__ A0, int lda0,
    const unsigned short* __restrict__ W0, int ldw0, int K0,
    const unsigned short* __restrict__ A1,   // hb_in [512,1024]
    const unsigned short* __restrict__ W1,   // Whh   [3072,1024]
    const float* __restrict__ bih, const float* __restrict__ bhh,
    const float* __restrict__ hf_in, float* __restrict__ hf_out,
    unsigned short* __restrict__ hb_out, unsigned short* __restrict__ slot)
{
    __shared__ __align__(16) unsigned short As2[2 * 32 * 32];
    __shared__ __align__(16) unsigned short Ws2[3 * 2 * 64 * 32];
    const int bm = blockIdx.y * 32;
    const int bn = blockIdx.x * 64;
    const int t = threadIdx.x;
    const int lane = t & 63;
    const int wv = t >> 6;
    const int ln = lane & 15;
    const int quad = lane >> 4;

    f32x4 accR[2], accZ[2], accN0[2], accN1[2];
    #pragma unroll
    for (int i = 0; i < 2; i++) {
        f32x4 z = {0.f, 0.f, 0.f, 0.f};
        accR[i] = z; accZ[i] = z; accN0[i] = z; accN1[i] = z;
    }

    gru_phase64(A0, lda0, W0, ldw0, K0, As2, Ws2, bm, bn, t, wv, ln, quad,
                accR, accZ, accN0);
    gru_phase64(A1, H_DIM, W1, H_DIM, H_DIM, As2, Ws2, bm, bn, t, wv, ln, quad,
                accR, accZ, accN1);

    const int n = bn + wv * 16 + ln;
    const float br = bih[n] + bhh[n];
    const float bz = bih[H_DIM + n] + bhh[H_DIM + n];
    const float bi_n = bih[2 * H_DIM + n];
    const float bh_n = bhh[2 * H_DIM + n];
    #pragma unroll
    for (int i = 0; i < 2; i++) {
        #pragma unroll
        for (int r = 0; r < 4; r++) {
            const int m = bm + i * 16 + quad * 4 + r;
            const size_t idx = (size_t)m * H_DIM + n;
            float rg = 1.f / (1.f + __expf(-(accR[i][r] + br)));
            float zg = 1.f / (1.f + __expf(-(accZ[i][r] + bz)));
            float av = accN0[i][r] + bi_n + rg * (accN1[i][r] + bh_n);
            float e2 = __expf(-2.f * fabsf(av));
            float th = (1.f - e2) / (1.f + e2);
            th = av < 0.f ? -th : th;
            float o = (1.f - zg) * th + zg * hf_in[idx];
            hf_out[idx] = o;
            unsigned short ob = f2b(o);
            hb_out[idx] = ob;
            if (slot) slot[idx] = ob;
        }
    }
}

// ---------------------------------------------------------------------------
// Fused attention: one block per batch row. scores = h.wAhT + attnx (bf16),
// softmax over 64, then ctx[b,:] = sum_l aw[l] * enc[l,b,:]. 512 blocks.
// ---------------------------------------------------------------------------
__global__ __launch_bounds__(256) void attn_ctx(
    const unsigned short* __restrict__ hb,     // [512,1024] bf16
    const unsigned short* __restrict__ wAhT,   // [1024][64] bf16 (k-major)
    const unsigned short* __restrict__ attnx_t,// [512,64] bf16 (incl bias)
    const unsigned short* __restrict__ encb,   // [64,512,1024] bf16
    unsigned short* __restrict__ ctx)          // [512,1024] bf16
{
    __shared__ float hf[H_DIM];
    __shared__ float part[4][S_LEN];
    __shared__ float awl[S_LEN];
    const int b = blockIdx.x, t = threadIdx.x;
    {
        us4 u = *(const us4*)(hb + ((size_t)b << 10) + t * 4);
        #pragma unroll
        for (int j = 0; j < 4; j++) hf[t * 4 + j] = b2f(u[j]);
    }
    __syncthreads();
    {
        const int c = t & 63, ks = (t >> 6) * 256;
        float s = 0.f;
        #pragma unroll 8
        for (int k = 0; k < 256; k++)
            s += hf[ks + k] * b2f(wAhT[(size_t)(ks + k) * S_LEN + c]);
        part[t >> 6][c] = s;
    }
    __syncthreads();
    if (t < 64) {
        float v = part[0][t] + part[1][t] + part[2][t] + part[3][t]
                + b2f(attnx_t[b * S_LEN + t]);
        float m = v;
        #pragma unroll
        for (int off = 32; off; off >>= 1) m = fmaxf(m, __shfl_xor(m, off));
        float e = __expf(v - m);
        float ss = e;
        #pragma unroll
        for (int off = 32; off; off >>= 1) ss += __shfl_xor(ss, off);
        awl[t] = e / ss;
    }
    __syncthreads();
    const int hq = t * 4;
    float s0 = 0.f, s1 = 0.f, s2 = 0.f, s3 = 0.f;
    #pragma unroll 4
    for (int l = 0; l < S_LEN; l++) {
        us4 u = *(const us4*)(encb + (((size_t)l * BATCH + b) << 10) + hq);
        float w = awl[l];
        s0 += w * b2f(u[0]); s1 += w * b2f(u[1]);
        s2 += w * b2f(u[2]); s3 += w * b2f(u[3]);
    }
    us4 o; o[0] = f2b(s0); o[1] = f2b(s1); o[2] = f2b(s2); o[3] = f2b(s3);
    *(us4*)(ctx + ((size_t)b << 10) + hq) = o;
}

// strided fp32 -> compact bf16 weight convert, 4 elems/thread (cols % 4 == 0)
__global__ void cvt_w4(const float* __restrict__ src, int ld,
                       unsigned short* __restrict__ dst, int rows, int cols)
{
    int idx = blockIdx.x * blockDim.x + threadIdx.x;
    int total4 = rows * cols / 4;
    if (idx >= total4) return;
    int e = idx * 4;
    int r = e / cols, c = e - r * cols;
    const float* s = src + (size_t)r * ld + c;
    us4 o;
    #pragma unroll
    for (int j = 0; j < 4; j++) o[j] = f2b(s[j]);
    *(us4*)(dst + e) = o;
}

// contiguous fp32 -> bf16, 4 elems/thread
__global__ void cvt_plain4(const float* __restrict__ src,
                           unsigned short* __restrict__ dst, int total4)
{
    int idx = blockIdx.x * blockDim.x + threadIdx.x;
    if (idx >= total4) return;
    f32x4 v = *(const f32x4*)(src + (size_t)idx * 4);
    us4 o;
    #pragma unroll
    for (int j = 0; j < 4; j++) o[j] = f2b(v[j]);
    *(us4*)(dst + (size_t)idx * 4) = o;
}

// fp32 [rows, scols] -> bf16 [rows, dcols] zero-padded
__global__ void cvt_pad(const float* __restrict__ src, int scols,
                        unsigned short* __restrict__ dst, int dcols, int total)
{
    int idx = blockIdx.x * blockDim.x + threadIdx.x;
    if (idx >= total) return;
    int r = idx / dcols, c = idx - r * dcols;
    dst[idx] = (c < scols) ? f2b(src[(size_t)r * scols + c]) : (unsigned short)0;
}

// attn_W[:, H:2H] fp32 [64, ld 2048] -> wAhT bf16 [k][c]
__global__ void cvt_attT(const float* __restrict__ attn_W,
                         unsigned short* __restrict__ dst)
{
    int idx = blockIdx.x * blockDim.x + threadIdx.x;
    if (idx >= S_LEN * H_DIM) return;
    int k = idx >> 6, c = idx & 63;
    dst[idx] = f2b(attn_W[(size_t)c * 2 * H_DIM + H_DIM + k]);
}

__global__ void log_softmax1024(float* __restrict__ x)
{
    __shared__ float red[256];
    float* xr = x + (size_t)blockIdx.x * O_DIM;
    int t = threadIdx.x;
    float m = -1e30f;
    for (int i = t; i < O_DIM; i += 256) m = fmaxf(m, xr[i]);
    red[t] = m; __syncthreads();
    for (int s2 = 128; s2 > 0; s2 >>= 1) {
        if (t < s2) red[t] = fmaxf(red[t], red[t + s2]);
        __syncthreads();
    }
    m = red[0];
    __syncthreads();
    float s = 0.f;
    for (int i = t; i < O_DIM; i += 256) s += expf(xr[i] - m);
    red[t] = s; __syncthreads();
    for (int s2 = 128; s2 > 0; s2 >>= 1) {
        if (t < s2) red[t] += red[t + s2];
        __syncthreads();
    }
    float lse = m + logf(red[0]);
    __syncthreads();
    for (int i = t; i < O_DIM; i += 256) xr[i] = xr[i] - lse;
}

// ---------------------------------------------------------------------------
extern "C" void kernel_launch(void* const* d_in, const int* in_sizes, int n_in,
                              void* d_out, int out_size, void* d_ws, size_t ws_size,
                              hipStream_t stream)
{
    const float* input   = (const float*)d_in[0];   // [S,B,IN]
    const float* target  = (const float*)d_in[1];   // [T,B,H]
    const float* enc_Wih = (const float*)d_in[2];
    const float* enc_Whh = (const float*)d_in[3];
    const float* enc_bih = (const float*)d_in[4];
    const float* enc_bhh = (const float*)d_in[5];
    const float* attn_W  = (const float*)d_in[6];   // [S,2H]
    const float* attn_b  = (const float*)d_in[7];
    const float* comb_W  = (const float*)d_in[8];   // [H,2H]
    const float* comb_b  = (const float*)d_in[9];
    const float* dec_Wih = (const float*)d_in[10];
    const float* dec_Whh = (const float*)d_in[11];
    const float* dec_bih = (const float*)d_in[12];
    const float* dec_bhh = (const float*)d_in[13];
    const float* out_W   = (const float*)d_in[14];
    const float* out_b   = (const float*)d_in[15];
    float* out = (float*)d_out;                     // [B,O] fp32

    // ---- workspace layout ----
    char* p = (char*)d_ws;
    auto alloc = [&](size_t bytes) {
        char* r = p; p += (bytes + 255) & ~(size_t)255; return r;
    };
    unsigned short* wWhh  = (unsigned short*)alloc((size_t)H3 * H_DIM * 2);
    unsigned short* wDih  = (unsigned short*)alloc((size_t)H3 * H_DIM * 2);
    unsigned short* wDhh  = (unsigned short*)alloc((size_t)H3 * H_DIM * 2);
    unsigned short* wCc   = (unsigned short*)alloc((size_t)H_DIM * H_DIM * 2);
    unsigned short* wCx   = (unsigned short*)alloc((size_t)H_DIM * H_DIM * 2);
    unsigned short* wO    = (unsigned short*)alloc((size_t)O_DIM * H_DIM * 2);
    unsigned short* wAhT  = (unsigned short*)alloc((size_t)H_DIM * S_LEN * 2);
    unsigned short* wAx   = (unsigned short*)alloc((size_t)S_LEN * H_DIM * 2);
    unsigned short* wIhp  = (unsigned short*)alloc((size_t)H3 * INP * 2);
    unsigned short* xbp   = (unsigned short*)alloc((size_t)S_LEN * BATCH * INP * 2);
    unsigned short* encb  = (unsigned short*)alloc((size_t)S_LEN * BATCH * H_DIM * 2);
    unsigned short* combx = (unsigned short*)alloc((size_t)(T_LEN - 1) * BATCH * H_DIM * 2);
    unsigned short* attnx = (unsigned short*)alloc((size_t)(T_LEN - 1) * BATCH * S_LEN * 2);
    float*          h     = (float*)alloc((size_t)BATCH * H_DIM * 4);
    unsigned short* hbA   = (unsigned short*)alloc((size_t)BATCH * H_DIM * 2);
    unsigned short* hbB   = (unsigned short*)alloc((size_t)BATCH * H_DIM * 2);
    unsigned short* ctx   = (unsigned short*)alloc((size_t)BATCH * H_DIM * 2);
    unsigned short* comb  = (unsigned short*)alloc((size_t)BATCH * H_DIM * 2);
    // targetb overlays encb: consumed (attnx/combx gemms) before encoder
    // writes encb. [32*512, 1024] bf16 = 33.5 MB inside encb's 64 MB.
    unsigned short* targetb = encb;

    const dim3 blk(256);

    hipMemsetAsync(h,   0, (size_t)BATCH * H_DIM * 4, stream);
    hipMemsetAsync(hbA, 0, (size_t)BATCH * H_DIM * 2, stream);

    // ---- one-time converts (all bf16) ----
    cvt_w4<<<(H3 * H_DIM / 4 + 255) / 256, blk, 0, stream>>>(enc_Whh, H_DIM, wWhh, H3, H_DIM);
    cvt_w4<<<(H3 * H_DIM / 4 + 255) / 256, blk, 0, stream>>>(dec_Wih, H_DIM, wDih, H3, H_DIM);
    cvt_w4<<<(H3 * H_DIM / 4 + 255) / 256, blk, 0, stream>>>(dec_Whh, H_DIM, wDhh, H3, H_DIM);
    cvt_w4<<<(H_DIM * H_DIM / 4 + 255) / 256, blk, 0, stream>>>(comb_W + H_DIM, 2 * H_DIM, wCc, H_DIM, H_DIM);
    cvt_w4<<<(H_DIM * H_DIM / 4 + 255) / 256, blk, 0, stream>>>(comb_W, 2 * H_DIM, wCx, H_DIM, H_DIM);
    cvt_w4<<<(O_DIM * H_DIM / 4 + 255) / 256, blk, 0, stream>>>(out_W, H_DIM, wO, O_DIM, H_DIM);
    cvt_w4<<<(S_LEN * H_DIM / 4 + 255) / 256, blk, 0, stream>>>(attn_W, 2 * H_DIM, wAx, S_LEN, H_DIM);
    cvt_attT<<<(S_LEN * H_DIM + 255) / 256, blk, 0, stream>>>(attn_W, wAhT);
    cvt_pad<<<((S_LEN * BATCH * INP) + 255) / 256, blk, 0, stream>>>(
        input, IN_DIM, xbp, INP, S_LEN * BATCH * INP);
    cvt_pad<<<((H3 * INP) + 255) / 256, blk, 0, stream>>>(
        enc_Wih, IN_DIM, wIhp, INP, H3 * INP);
    cvt_plain4<<<((T_LEN * BATCH * H_DIM / 4) + 255) / 256, blk, 0, stream>>>(
        target, targetb, T_LEN * BATCH * H_DIM / 4);

    const int MT = (T_LEN - 1) * BATCH;  // 15872
    // attnx = target @ attn_W[:, :H]^T + attn_b  (bf16 fast path)
    gemm_k<64><<<dim3(1, MT / 64), blk, 0, stream>>>(
        targetb, H_DIM, wAx, H_DIM, attn_b,
        nullptr, nullptr, 0, nullptr, attnx, S_LEN, H_DIM, 1 | 32);
    // combx = target @ comb_W[:, :H]^T + comb_b  (bf16 fast path)
    gemm_k<128><<<dim3(H_DIM / 128, MT / 64), blk, 0, stream>>>(
        targetb, H_DIM, wCx, H_DIM, comb_b,
        nullptr, nullptr, 0, nullptr, combx, H_DIM, H_DIM, 1 | 32);

    const dim3 grid_gru(H_DIM / 64, BATCH / 32);   // 16 x 16 = 256 blocks
    unsigned short* hcur = hbA;
    unsigned short* hnxt = hbB;

    // ---------------- encoder: one kernel per step ----------------
    for (int s = 0; s < S_LEN; s++) {
        gru_gemm<<<grid_gru, blk, 0, stream>>>(
            xbp + (size_t)s * BATCH * INP, INP, wIhp, INP, INP,
            hcur, wWhh, enc_bih, enc_bhh, h, h, hnxt,
            encb + (size_t)s * BATCH * H_DIM);
        unsigned short* tmp = hcur; hcur = hnxt; hnxt = tmp;
    }

    // ---------------- decoder: three kernels per step ----------------
    for (int t = 0; t < T_LEN - 1; t++) {
        attn_ctx<<<BATCH, blk, 0, stream>>>(
            hcur, wAhT, attnx + (size_t)t * BATCH * S_LEN, encb, ctx);
        gemm_k<64><<<dim3(H_DIM / 64, BATCH / 64), blk, 0, stream>>>(
            ctx, H_DIM, wCc, H_DIM, nullptr,
            nullptr, combx + (size_t)t * BATCH * H_DIM, H_DIM,
            nullptr, comb, H_DIM, H_DIM, 4 | 8 | 32);
        gru_gemm<<<grid_gru, blk, 0, stream>>>(
            comb, H_DIM, wDih, H_DIM, H_DIM,
            hcur, wDhh, dec_bih, dec_bhh, h, h, hnxt, nullptr);
        unsigned short* tmp = hcur; hcur = hnxt; hnxt = tmp;
    }

    // ---------------- output ----------------
    gemm_k<64><<<dim3(O_DIM / 64, BATCH / 64), blk, 0, stream>>>(
        hcur, H_DIM, wO, H_DIM, out_b,
        nullptr, nullptr, 0, out, nullptr, O_DIM, H_DIM, 1 | 16);
    log_softmax1024<<<BATCH, blk, 0, stream>>>(out);
}

// Round 5
// 3123.241 us; speedup vs baseline: 10.6562x; 1.1662x over previous
//
#include <hip/hip_runtime.h>
#include <hip/hip_bf16.h>
#include <math.h>

#define S_LEN 64
#define T_LEN 32
#define BATCH 512
#define IN_DIM 66
#define INP 128         // IN_DIM zero-padded to multiple of 64
#define H_DIM 1024
#define O_DIM 1024
#define H3 3072

typedef __attribute__((ext_vector_type(8))) short short8;
typedef __attribute__((ext_vector_type(4))) float f32x4;
typedef __attribute__((ext_vector_type(4))) unsigned short us4;

__device__ __forceinline__ unsigned short f2b(float f) {
    union { float f; unsigned u; } x; x.f = f;
    unsigned r = x.u + 0x7FFF + ((x.u >> 16) & 1);
    return (unsigned short)(r >> 16);
}
__device__ __forceinline__ float b2f(unsigned short s) {
    union { unsigned u; float f; } x; x.u = ((unsigned)s) << 16;
    return x.f;
}
// async global->LDS, 16B per lane; lds base must be wave-uniform
__device__ __forceinline__ void gll16(const void* g, const void* l) {
    __builtin_amdgcn_global_load_lds(
        (const __attribute__((address_space(1))) unsigned int*)g,
        (__attribute__((address_space(3))) unsigned int*)l, 16, 0, 0);
}

// ---------------------------------------------------------------------------
// MFMA GEMM, bf16: C[M,N] = A@W^T, tile TM x TN. lda/ldw mult of 8, K mult 32.
// flags: 1 bias, 2 add fp32, 4 add bf16, 8 relu, 16 store f32, 32 store bf16
// ---------------------------------------------------------------------------
template<int TM, int TN>
__global__ __launch_bounds__(256) void gemm_k(
    const unsigned short* __restrict__ A, int lda,
    const unsigned short* __restrict__ W, int ldw,
    const float* __restrict__ bias,
    const float* __restrict__ addf, const unsigned short* __restrict__ addb,
    int ldadd,
    float* __restrict__ Cf,
    unsigned short* __restrict__ Cb, int ldc,
    int K, int flags)
{
    constexpr int IF = TM / 16;   // A frags per wave
    constexpr int JF = TN / 64;   // B frags per wave
    constexpr int NW = TN / 4;    // cols per wave
    constexpr int CA = TM * 4;    // 16B chunks in A tile
    constexpr int CW = TN * 4;
    __shared__ __align__(16) unsigned short As[TM * 32];
    __shared__ __align__(16) unsigned short Bs[TN * 32];

    const int bm = blockIdx.y * TM;
    const int bn = blockIdx.x * TN;
    const int t = threadIdx.x;
    const int lane = t & 63;
    const int wv = t >> 6;
    const int ln = lane & 15;
    const int quad = lane >> 4;

    f32x4 acc[IF][JF];
    #pragma unroll
    for (int i = 0; i < IF; i++)
        #pragma unroll
        for (int j = 0; j < JF; j++) {
            f32x4 z = {0.f, 0.f, 0.f, 0.f};
            acc[i][j] = z;
        }

    for (int k0 = 0; k0 < K; k0 += 32) {
        if constexpr (CA >= 256) {
            #pragma unroll
            for (int j = 0; j < CA / 256; j++) {
                int ch = j * 256 + t;
                gll16(A + (size_t)(bm + (ch >> 2)) * lda + k0 + (ch & 3) * 8,
                      (const char*)As + (j * 4 + wv) * 1024);
            }
        } else {
            if (t < CA)
                gll16(A + (size_t)(bm + (t >> 2)) * lda + k0 + (t & 3) * 8,
                      (const char*)As + wv * 1024);
        }
        if constexpr (CW >= 256) {
            #pragma unroll
            for (int j = 0; j < CW / 256; j++) {
                int ch = j * 256 + t;
                gll16(W + (size_t)(bn + (ch >> 2)) * ldw + k0 + (ch & 3) * 8,
                      (const char*)Bs + (j * 4 + wv) * 1024);
            }
        } else {
            if (t < CW)
                gll16(W + (size_t)(bn + (t >> 2)) * ldw + k0 + (t & 3) * 8,
                      (const char*)Bs + wv * 1024);
        }
        __syncthreads();
        short8 af[IF], bf[JF];
        #pragma unroll
        for (int i = 0; i < IF; i++)
            af[i] = *(const short8*)&As[(i * 16 + ln) * 32 + quad * 8];
        #pragma unroll
        for (int j = 0; j < JF; j++)
            bf[j] = *(const short8*)&Bs[(wv * NW + j * 16 + ln) * 32 + quad * 8];
        #pragma unroll
        for (int i = 0; i < IF; i++)
            #pragma unroll
            for (int j = 0; j < JF; j++)
                acc[i][j] = __builtin_amdgcn_mfma_f32_16x16x32_bf16(
                    af[i], bf[j], acc[i][j], 0, 0, 0);
        __syncthreads();
    }

    #pragma unroll
    for (int i = 0; i < IF; i++) {
        #pragma unroll
        for (int j = 0; j < JF; j++) {
            #pragma unroll
            for (int r = 0; r < 4; r++) {
                int m = bm + i * 16 + quad * 4 + r;
                int n = bn + wv * NW + j * 16 + ln;
                float v = acc[i][j][r];
                if (flags & 1) v += bias[n];
                if (flags & 2) v += addf[(size_t)m * ldadd + n];
                if (flags & 4) v += b2f(addb[(size_t)m * ldadd + n]);
                if (flags & 8) v = fmaxf(v, 0.f);
                if (flags & 16) Cf[(size_t)m * ldc + n] = v;
                if (flags & 32) Cb[(size_t)m * ldc + n] = f2b(v);
            }
        }
    }
}

// ---------------------------------------------------------------------------
// One BK=64 tile of a GRU phase for one wave-group (256 threads).
// As_g: 2*32*32 shorts (4 KB), Ws_g: 3*2*64*32 shorts (24 KB).
// ---------------------------------------------------------------------------
__device__ __forceinline__ void gru_tile(
    const unsigned short* __restrict__ A, int lda,
    const unsigned short* __restrict__ W, int ldw, int kb,
    unsigned short* As_g, unsigned short* Ws_g,
    int bm, int bn, int gt, int gwv, int ln, int quad,
    f32x4 (&accR)[2], f32x4 (&accZ)[2], f32x4 (&accN)[2])
{
    // A: 256 chunks: sub gt>>7, row (gt>>2)&31, kchunk gt&3
    {
        int s = gt >> 7, r = (gt >> 2) & 31, c = gt & 3;
        gll16(A + (size_t)(bm + r) * lda + kb + s * 32 + c * 8,
              (const char*)As_g + gwv * 1024);
    }
    // W: 1536 chunks (512/gate): ch -> gate ch>>9; ch2=ch&511: sub ch2>>8,
    // row (ch2>>2)&63, kchunk ch2&3
    #pragma unroll
    for (int j = 0; j < 6; j++) {
        int ch = j * 256 + gt;
        int g2 = ch >> 9, ch2 = ch & 511;
        int s = ch2 >> 8, r = (ch2 >> 2) & 63, c = ch2 & 3;
        gll16(W + (size_t)(g2 * H_DIM + bn + r) * ldw + kb + s * 32 + c * 8,
              (const char*)Ws_g + j * 4096 + gwv * 1024);
    }
    __syncthreads();
    #pragma unroll
    for (int sub = 0; sub < 2; sub++) {
        short8 a[2], bw[3];
        #pragma unroll
        for (int i = 0; i < 2; i++)
            a[i] = *(const short8*)&As_g[sub * 1024 + (i * 16 + ln) * 32 + quad * 8];
        #pragma unroll
        for (int g = 0; g < 3; g++)
            bw[g] = *(const short8*)&Ws_g[g * 4096 + sub * 2048 + (gwv * 16 + ln) * 32 + quad * 8];
        #pragma unroll
        for (int i = 0; i < 2; i++) {
            accR[i] = __builtin_amdgcn_mfma_f32_16x16x32_bf16(a[i], bw[0], accR[i], 0, 0, 0);
            accZ[i] = __builtin_amdgcn_mfma_f32_16x16x32_bf16(a[i], bw[1], accZ[i], 0, 0, 0);
            accN[i] = __builtin_amdgcn_mfma_f32_16x16x32_bf16(a[i], bw[2], accN[i], 0, 0, 0);
        }
    }
    __syncthreads();
}

// ---------------------------------------------------------------------------
// Fused GRU step, 512 threads: two 4-wave groups K-split the GEMMs
// (group g: k in [g*K/2, (g+1)*K/2) of both phases) -> 2 waves/SIMD for
// latency overlap at unchanged weight traffic. LDS cross-group reduction,
// then group 0 runs the GRU elementwise epilogue.
// Tile 32 batch x 64 gate cols; grid (16,16) = 256 blocks.
// K0 must be a multiple of 128; phase-1 K fixed at 1024.
// ---------------------------------------------------------------------------
__global__ __launch_bounds__(512) void gru_gemm(
    const unsigned short* __restrict__ A0, int lda0,
    const unsigned short* __restrict__ W0, int ldw0, int K0,
    const unsigned short* __restrict__ A1,   // hb_in [512,1024]
    const unsigned short* __restrict__ W1,   // Whh   [3072,1024]
    const float* __restrict__ bih, const float* __restrict__ bhh,
    const float* __restrict__ hf_in, float* __restrict__ hf_out,
    unsigned short* __restrict__ hb_out, unsigned short* __restrict__ slot)
{
    __shared__ __align__(16) unsigned short As2[2][2 * 32 * 32];      // 8 KB
    __shared__ __align__(16) unsigned short Ws2[2][3 * 2 * 64 * 32];  // 48 KB
    const int bm = blockIdx.y * 32;
    const int bn = blockIdx.x * 64;
    const int t = threadIdx.x;            // 0..511
    const int wg = t >> 8;                // wave-group
    const int gt = t & 255;
    const int lane = t & 63;
    const int gwv = gt >> 6;              // wave within group
    const int ln = lane & 15;
    const int quad = lane >> 4;

    unsigned short* As_g = As2[wg];
    unsigned short* Ws_g = Ws2[wg];

    f32x4 accR[2], accZ[2], accN0[2], accN1[2];
    #pragma unroll
    for (int i = 0; i < 2; i++) {
        f32x4 z = {0.f, 0.f, 0.f, 0.f};
        accR[i] = z; accZ[i] = z; accN0[i] = z; accN1[i] = z;
    }

    const int half0 = K0 >> 1;            // multiple of 64
    for (int k0 = 0; k0 < half0; k0 += 64)
        gru_tile(A0, lda0, W0, ldw0, wg * half0 + k0, As_g, Ws_g,
                 bm, bn, gt, gwv, ln, quad, accR, accZ, accN0);
    for (int k0 = 0; k0 < 512; k0 += 64)
        gru_tile(A1, H_DIM, W1, H_DIM, wg * 512 + k0, As_g, Ws_g,
                 bm, bn, gt, gwv, ln, quad, accR, accZ, accN1);

    // ---- cross-group reduction (stride 33 floats: conflict-free) ----
    float* red = (float*)Ws2;             // 48 KB scratch, needs 33.8 KB
    const int rb = (gwv * 64 + lane) * 33;
    if (wg == 1) {
        #pragma unroll
        for (int i = 0; i < 2; i++)
            #pragma unroll
            for (int r = 0; r < 4; r++) {
                red[rb + i * 4 + r]      = accR[i][r];
                red[rb + 8 + i * 4 + r]  = accZ[i][r];
                red[rb + 16 + i * 4 + r] = accN0[i][r];
                red[rb + 24 + i * 4 + r] = accN1[i][r];
            }
    }
    __syncthreads();
    if (wg == 0) {
        #pragma unroll
        for (int i = 0; i < 2; i++)
            #pragma unroll
            for (int r = 0; r < 4; r++) {
                accR[i][r]  += red[rb + i * 4 + r];
                accZ[i][r]  += red[rb + 8 + i * 4 + r];
                accN0[i][r] += red[rb + 16 + i * 4 + r];
                accN1[i][r] += red[rb + 24 + i * 4 + r];
            }
        const int n = bn + gwv * 16 + ln;
        const float br = bih[n] + bhh[n];
        const float bz = bih[H_DIM + n] + bhh[H_DIM + n];
        const float bi_n = bih[2 * H_DIM + n];
        const float bh_n = bhh[2 * H_DIM + n];
        #pragma unroll
        for (int i = 0; i < 2; i++) {
            #pragma unroll
            for (int r = 0; r < 4; r++) {
                const int m = bm + i * 16 + quad * 4 + r;
                const size_t idx = (size_t)m * H_DIM + n;
                float rg = 1.f / (1.f + __expf(-(accR[i][r] + br)));
                float zg = 1.f / (1.f + __expf(-(accZ[i][r] + bz)));
                float av = accN0[i][r] + bi_n + rg * (accN1[i][r] + bh_n);
                float e2 = __expf(-2.f * fabsf(av));
                float th = (1.f - e2) / (1.f + e2);
                th = av < 0.f ? -th : th;
                float o = (1.f - zg) * th + zg * hf_in[idx];
                hf_out[idx] = o;
                unsigned short ob = f2b(o);
                hb_out[idx] = ob;
                if (slot) slot[idx] = ob;
            }
        }
    }
}

// ---------------------------------------------------------------------------
// Fused attention: one block per batch row. scores = h.wAhT + attnx (bf16),
// softmax over 64, then ctx[b,:] = sum_l aw[l] * enc[l,b,:]. 512 blocks.
// ---------------------------------------------------------------------------
__global__ __launch_bounds__(256) void attn_ctx(
    const unsigned short* __restrict__ hb,     // [512,1024] bf16
    const unsigned short* __restrict__ wAhT,   // [1024][64] bf16 (k-major)
    const unsigned short* __restrict__ attnx_t,// [512,64] bf16 (incl bias)
    const unsigned short* __restrict__ encb,   // [64,512,1024] bf16
    unsigned short* __restrict__ ctx)          // [512,1024] bf16
{
    __shared__ float hf[H_DIM];
    __shared__ float part[4][S_LEN];
    __shared__ float awl[S_LEN];
    const int b = blockIdx.x, t = threadIdx.x;
    {
        us4 u = *(const us4*)(hb + ((size_t)b << 10) + t * 4);
        #pragma unroll
        for (int j = 0; j < 4; j++) hf[t * 4 + j] = b2f(u[j]);
    }
    __syncthreads();
    {
        const int c = t & 63, ks = (t >> 6) * 256;
        float s = 0.f;
        #pragma unroll 8
        for (int k = 0; k < 256; k++)
            s += hf[ks + k] * b2f(wAhT[(size_t)(ks + k) * S_LEN + c]);
        part[t >> 6][c] = s;
    }
    __syncthreads();
    if (t < 64) {
        float v = part[0][t] + part[1][t] + part[2][t] + part[3][t]
                + b2f(attnx_t[b * S_LEN + t]);
        float m = v;
        #pragma unroll
        for (int off = 32; off; off >>= 1) m = fmaxf(m, __shfl_xor(m, off));
        float e = __expf(v - m);
        float ss = e;
        #pragma unroll
        for (int off = 32; off; off >>= 1) ss += __shfl_xor(ss, off);
        awl[t] = e / ss;
    }
    __syncthreads();
    const int hq = t * 4;
    float s0 = 0.f, s1 = 0.f, s2 = 0.f, s3 = 0.f;
    #pragma unroll 4
    for (int l = 0; l < S_LEN; l++) {
        us4 u = *(const us4*)(encb + (((size_t)l * BATCH + b) << 10) + hq);
        float w = awl[l];
        s0 += w * b2f(u[0]); s1 += w * b2f(u[1]);
        s2 += w * b2f(u[2]); s3 += w * b2f(u[3]);
    }
    us4 o; o[0] = f2b(s0); o[1] = f2b(s1); o[2] = f2b(s2); o[3] = f2b(s3);
    *(us4*)(ctx + ((size_t)b << 10) + hq) = o;
}

// strided fp32 -> compact bf16 weight convert, 4 elems/thread (cols % 4 == 0)
__global__ void cvt_w4(const float* __restrict__ src, int ld,
                       unsigned short* __restrict__ dst, int rows, int cols)
{
    int idx = blockIdx.x * blockDim.x + threadIdx.x;
    int total4 = rows * cols / 4;
    if (idx >= total4) return;
    int e = idx * 4;
    int r = e / cols, c = e - r * cols;
    const float* s = src + (size_t)r * ld + c;
    us4 o;
    #pragma unroll
    for (int j = 0; j < 4; j++) o[j] = f2b(s[j]);
    *(us4*)(dst + e) = o;
}

// contiguous fp32 -> bf16, 4 elems/thread
__global__ void cvt_plain4(const float* __restrict__ src,
                           unsigned short* __restrict__ dst, int total4)
{
    int idx = blockIdx.x * blockDim.x + threadIdx.x;
    if (idx >= total4) return;
    f32x4 v = *(const f32x4*)(src + (size_t)idx * 4);
    us4 o;
    #pragma unroll
    for (int j = 0; j < 4; j++) o[j] = f2b(v[j]);
    *(us4*)(dst + (size_t)idx * 4) = o;
}

// fp32 [rows, scols] -> bf16 [rows, dcols] zero-padded
__global__ void cvt_pad(const float* __restrict__ src, int scols,
                        unsigned short* __restrict__ dst, int dcols, int total)
{
    int idx = blockIdx.x * blockDim.x + threadIdx.x;
    if (idx >= total) return;
    int r = idx / dcols, c = idx - r * dcols;
    dst[idx] = (c < scols) ? f2b(src[(size_t)r * scols + c]) : (unsigned short)0;
}

// attn_W[:, H:2H] fp32 [64, ld 2048] -> wAhT bf16 [k][c]
__global__ void cvt_attT(const float* __restrict__ attn_W,
                         unsigned short* __restrict__ dst)
{
    int idx = blockIdx.x * blockDim.x + threadIdx.x;
    if (idx >= S_LEN * H_DIM) return;
    int k = idx >> 6, c = idx & 63;
    dst[idx] = f2b(attn_W[(size_t)c * 2 * H_DIM + H_DIM + k]);
}

__global__ void log_softmax1024(float* __restrict__ x)
{
    __shared__ float red[256];
    float* xr = x + (size_t)blockIdx.x * O_DIM;
    int t = threadIdx.x;
    float m = -1e30f;
    for (int i = t; i < O_DIM; i += 256) m = fmaxf(m, xr[i]);
    red[t] = m; __syncthreads();
    for (int s2 = 128; s2 > 0; s2 >>= 1) {
        if (t < s2) red[t] = fmaxf(red[t], red[t + s2]);
        __syncthreads();
    }
    m = red[0];
    __syncthreads();
    float s = 0.f;
    for (int i = t; i < O_DIM; i += 256) s += expf(xr[i] - m);
    red[t] = s; __syncthreads();
    for (int s2 = 128; s2 > 0; s2 >>= 1) {
        if (t < s2) red[t] += red[t + s2];
        __syncthreads();
    }
    float lse = m + logf(red[0]);
    __syncthreads();
    for (int i = t; i < O_DIM; i += 256) xr[i] = xr[i] - lse;
}

// ---------------------------------------------------------------------------
extern "C" void kernel_launch(void* const* d_in, const int* in_sizes, int n_in,
                              void* d_out, int out_size, void* d_ws, size_t ws_size,
                              hipStream_t stream)
{
    const float* input   = (const float*)d_in[0];   // [S,B,IN]
    const float* target  = (const float*)d_in[1];   // [T,B,H]
    const float* enc_Wih = (const float*)d_in[2];
    const float* enc_Whh = (const float*)d_in[3];
    const float* enc_bih = (const float*)d_in[4];
    const float* enc_bhh = (const float*)d_in[5];
    const float* attn_W  = (const float*)d_in[6];   // [S,2H]
    const float* attn_b  = (const float*)d_in[7];
    const float* comb_W  = (const float*)d_in[8];   // [H,2H]
    const float* comb_b  = (const float*)d_in[9];
    const float* dec_Wih = (const float*)d_in[10];
    const float* dec_Whh = (const float*)d_in[11];
    const float* dec_bih = (const float*)d_in[12];
    const float* dec_bhh = (const float*)d_in[13];
    const float* out_W   = (const float*)d_in[14];
    const float* out_b   = (const float*)d_in[15];
    float* out = (float*)d_out;                     // [B,O] fp32

    // ---- workspace layout ----
    char* p = (char*)d_ws;
    auto alloc = [&](size_t bytes) {
        char* r = p; p += (bytes + 255) & ~(size_t)255; return r;
    };
    unsigned short* wWhh  = (unsigned short*)alloc((size_t)H3 * H_DIM * 2);
    unsigned short* wDih  = (unsigned short*)alloc((size_t)H3 * H_DIM * 2);
    unsigned short* wDhh  = (unsigned short*)alloc((size_t)H3 * H_DIM * 2);
    unsigned short* wCc   = (unsigned short*)alloc((size_t)H_DIM * H_DIM * 2);
    unsigned short* wCx   = (unsigned short*)alloc((size_t)H_DIM * H_DIM * 2);
    unsigned short* wO    = (unsigned short*)alloc((size_t)O_DIM * H_DIM * 2);
    unsigned short* wAhT  = (unsigned short*)alloc((size_t)H_DIM * S_LEN * 2);
    unsigned short* wAx   = (unsigned short*)alloc((size_t)S_LEN * H_DIM * 2);
    unsigned short* wIhp  = (unsigned short*)alloc((size_t)H3 * INP * 2);
    unsigned short* xbp   = (unsigned short*)alloc((size_t)S_LEN * BATCH * INP * 2);
    unsigned short* encb  = (unsigned short*)alloc((size_t)S_LEN * BATCH * H_DIM * 2);
    unsigned short* combx = (unsigned short*)alloc((size_t)(T_LEN - 1) * BATCH * H_DIM * 2);
    unsigned short* attnx = (unsigned short*)alloc((size_t)(T_LEN - 1) * BATCH * S_LEN * 2);
    float*          h     = (float*)alloc((size_t)BATCH * H_DIM * 4);
    unsigned short* hbA   = (unsigned short*)alloc((size_t)BATCH * H_DIM * 2);
    unsigned short* hbB   = (unsigned short*)alloc((size_t)BATCH * H_DIM * 2);
    unsigned short* ctx   = (unsigned short*)alloc((size_t)BATCH * H_DIM * 2);
    unsigned short* comb  = (unsigned short*)alloc((size_t)BATCH * H_DIM * 2);
    // targetb overlays encb: consumed (attnx/combx gemms) before encoder
    // writes encb. [32*512, 1024] bf16 = 33.5 MB inside encb's 64 MB.
    unsigned short* targetb = encb;

    const dim3 blk(256);

    hipMemsetAsync(h,   0, (size_t)BATCH * H_DIM * 4, stream);
    hipMemsetAsync(hbA, 0, (size_t)BATCH * H_DIM * 2, stream);

    // ---- one-time converts (all bf16) ----
    cvt_w4<<<(H3 * H_DIM / 4 + 255) / 256, blk, 0, stream>>>(enc_Whh, H_DIM, wWhh, H3, H_DIM);
    cvt_w4<<<(H3 * H_DIM / 4 + 255) / 256, blk, 0, stream>>>(dec_Wih, H_DIM, wDih, H3, H_DIM);
    cvt_w4<<<(H3 * H_DIM / 4 + 255) / 256, blk, 0, stream>>>(dec_Whh, H_DIM, wDhh, H3, H_DIM);
    cvt_w4<<<(H_DIM * H_DIM / 4 + 255) / 256, blk, 0, stream>>>(comb_W + H_DIM, 2 * H_DIM, wCc, H_DIM, H_DIM);
    cvt_w4<<<(H_DIM * H_DIM / 4 + 255) / 256, blk, 0, stream>>>(comb_W, 2 * H_DIM, wCx, H_DIM, H_DIM);
    cvt_w4<<<(O_DIM * H_DIM / 4 + 255) / 256, blk, 0, stream>>>(out_W, H_DIM, wO, O_DIM, H_DIM);
    cvt_w4<<<(S_LEN * H_DIM / 4 + 255) / 256, blk, 0, stream>>>(attn_W, 2 * H_DIM, wAx, S_LEN, H_DIM);
    cvt_attT<<<(S_LEN * H_DIM + 255) / 256, blk, 0, stream>>>(attn_W, wAhT);
    cvt_pad<<<((S_LEN * BATCH * INP) + 255) / 256, blk, 0, stream>>>(
        input, IN_DIM, xbp, INP, S_LEN * BATCH * INP);
    cvt_pad<<<((H3 * INP) + 255) / 256, blk, 0, stream>>>(
        enc_Wih, IN_DIM, wIhp, INP, H3 * INP);
    cvt_plain4<<<((T_LEN * BATCH * H_DIM / 4) + 255) / 256, blk, 0, stream>>>(
        target, targetb, T_LEN * BATCH * H_DIM / 4);

    const int MT = (T_LEN - 1) * BATCH;  // 15872
    // attnx = target @ attn_W[:, :H]^T + attn_b
    gemm_k<64, 64><<<dim3(1, MT / 64), blk, 0, stream>>>(
        targetb, H_DIM, wAx, H_DIM, attn_b,
        nullptr, nullptr, 0, nullptr, attnx, S_LEN, H_DIM, 1 | 32);
    // combx = target @ comb_W[:, :H]^T + comb_b  (128x128 tile, 992 blocks)
    gemm_k<128, 128><<<dim3(H_DIM / 128, MT / 128), blk, 0, stream>>>(
        targetb, H_DIM, wCx, H_DIM, comb_b,
        nullptr, nullptr, 0, nullptr, combx, H_DIM, H_DIM, 1 | 32);

    const dim3 grid_gru(H_DIM / 64, BATCH / 32);   // 16 x 16 = 256 blocks
    const dim3 blk512(512);
    unsigned short* hcur = hbA;
    unsigned short* hnxt = hbB;

    // ---------------- encoder: one kernel per step ----------------
    for (int s = 0; s < S_LEN; s++) {
        gru_gemm<<<grid_gru, blk512, 0, stream>>>(
            xbp + (size_t)s * BATCH * INP, INP, wIhp, INP, INP,
            hcur, wWhh, enc_bih, enc_bhh, h, h, hnxt,
            encb + (size_t)s * BATCH * H_DIM);
        unsigned short* tmp = hcur; hcur = hnxt; hnxt = tmp;
    }

    // ---------------- decoder: three kernels per step ----------------
    for (int t = 0; t < T_LEN - 1; t++) {
        attn_ctx<<<BATCH, blk, 0, stream>>>(
            hcur, wAhT, attnx + (size_t)t * BATCH * S_LEN, encb, ctx);
        gemm_k<32, 64><<<dim3(H_DIM / 64, BATCH / 32), blk, 0, stream>>>(
            ctx, H_DIM, wCc, H_DIM, nullptr,
            nullptr, combx + (size_t)t * BATCH * H_DIM, H_DIM,
            nullptr, comb, H_DIM, H_DIM, 4 | 8 | 32);
        gru_gemm<<<grid_gru, blk512, 0, stream>>>(
            comb, H_DIM, wDih, H_DIM, H_DIM,
            hcur, wDhh, dec_bih, dec_bhh, h, h, hnxt, nullptr);
        unsigned short* tmp = hcur; hcur = hnxt; hnxt = tmp;
    }

    // ---------------- output ----------------
    gemm_k<32, 64><<<dim3(O_DIM / 64, BATCH / 32), blk, 0, stream>>>(
        hcur, H_DIM, wO, H_DIM, out_b,
        nullptr, nullptr, 0, out, nullptr, O_DIM, H_DIM, 1 | 16);
    log_softmax1024<<<BATCH, blk, 0, stream>>>(out);
}